// Round 1
// baseline (2021.964 us; speedup 1.0000x reference)
//
#include <hip/hip_runtime.h>

#define N_NODES 100000
#define N_HEDGES 25000
#define N_EDGES 1000000
#define NG 64
#define HD 64

// ---------------- utility ----------------
__global__ void zero_f32(float* p, int n) {
    int i = blockIdx.x * blockDim.x + threadIdx.x;
    int stride = gridDim.x * blockDim.x;
    for (; i < n; i += stride) p[i] = 0.f;
}

// counts of incoming edges per dst (hyperedge and node), computed once
__global__ void count_kernel(const int* __restrict__ n2e_dst,
                             const int* __restrict__ e2n_dst,
                             float* __restrict__ cnt_e,
                             float* __restrict__ cnt_n) {
    int i = blockIdx.x * blockDim.x + threadIdx.x;
    if (i < N_EDGES) {
        atomicAdd(&cnt_e[n2e_dst[i]], 1.f);
        atomicAdd(&cnt_n[e2n_dst[i]], 1.f);
    }
}

__global__ void batch_count_kernel(const int* __restrict__ node_batch,
                                   const int* __restrict__ edge_batch,
                                   float* __restrict__ cntBN,
                                   float* __restrict__ cntBE) {
    int i = blockIdx.x * blockDim.x + threadIdx.x;
    if (i < N_NODES) atomicAdd(&cntBN[node_batch[i]], 1.f);
    if (i < N_HEDGES) atomicAdd(&cntBE[edge_batch[i]], 1.f);
}

// xn = relu(node_x @ Wn + bn)   node_x:[N,1]  Wn:[1,64]
__global__ void encode_nodes(const float* __restrict__ node_x,
                             const float* __restrict__ Wn,
                             const float* __restrict__ bn,
                             float* __restrict__ xn) {
    int i = blockIdx.x * blockDim.x + threadIdx.x;
    if (i >= N_NODES * HD) return;
    int node = i >> 6, h = i & 63;
    float v = node_x[node] * Wn[h] + bn[h];
    xn[i] = v > 0.f ? v : 0.f;
}

// xe = relu(edge_x @ We + be)   edge_x:[E,2]  We:[2,64]
__global__ void encode_edges(const float* __restrict__ edge_x,
                             const float* __restrict__ We,
                             const float* __restrict__ be,
                             float* __restrict__ xe) {
    int i = blockIdx.x * blockDim.x + threadIdx.x;
    if (i >= N_HEDGES * HD) return;
    int e = i >> 6, h = i & 63;
    float v = edge_x[2 * e] * We[h] + edge_x[2 * e + 1] * We[HD + h] + be[h];
    xe[i] = v > 0.f ? v : 0.f;
}

// scatter-add: agg[dst[e]] += xsrc[src[e]]   (one wave per edge, lane = feature)
__global__ void scatter_add(const float* __restrict__ xsrc,
                            const int* __restrict__ src,
                            const int* __restrict__ dst,
                            float* __restrict__ agg) {
    long total = (long)N_EDGES * HD;
    long stride = (long)gridDim.x * blockDim.x;
    for (long i = (long)blockIdx.x * blockDim.x + threadIdx.x; i < total; i += stride) {
        int e = (int)(i >> 6), h = (int)(i & 63);
        int s = src[e], d = dst[e];
        atomicAdd(&agg[(long)d * HD + h], xsrc[(long)s * HD + h]);
    }
}

// out = relu( (agg*inv) @ Wl + bl + xdst @ Wr ), weights staged in LDS
__global__ void sage_combine(const float* __restrict__ agg,
                             const float* __restrict__ cnt,
                             const float* __restrict__ xdst,
                             const float* __restrict__ Wl,
                             const float* __restrict__ bl,
                             const float* __restrict__ Wr,
                             float* __restrict__ out, int rows) {
    __shared__ float sWl[HD * HD];
    __shared__ float sWr[HD * HD];
    for (int t = threadIdx.x; t < HD * HD; t += blockDim.x) {
        sWl[t] = Wl[t];
        sWr[t] = Wr[t];
    }
    __syncthreads();
    long total = (long)rows * HD;
    long stride = (long)gridDim.x * blockDim.x;
    for (long i = (long)blockIdx.x * blockDim.x + threadIdx.x; i < total; i += stride) {
        int r = (int)(i >> 6), h = (int)(i & 63);
        float inv = 1.f / fmaxf(cnt[r], 1.f);
        const float* ar = agg + (long)r * HD;
        const float* xr = xdst + (long)r * HD;
        float sa = 0.f, sx = 0.f;
#pragma unroll
        for (int k = 0; k < HD; k++) {
            sa += ar[k] * sWl[k * HD + h];
            sx += xr[k] * sWr[k * HD + h];
        }
        float v = sa * inv + sx + bl[h];
        out[i] = v > 0.f ? v : 0.f;
    }
}

// segment-sum pool into [NG,HD] with LDS staging (batch is sorted but we don't rely on it)
__global__ void pool_kernel(const float* __restrict__ x,
                            const int* __restrict__ batch,
                            float* __restrict__ pool, int rows) {
    __shared__ float sp[NG * HD];  // 16 KB
    for (int t = threadIdx.x; t < NG * HD; t += blockDim.x) sp[t] = 0.f;
    __syncthreads();
    long total = (long)rows * HD;
    long stride = (long)gridDim.x * blockDim.x;
    for (long i = (long)blockIdx.x * blockDim.x + threadIdx.x; i < total; i += stride) {
        int r = (int)(i >> 6), h = (int)(i & 63);
        atomicAdd(&sp[batch[r] * HD + h], x[i]);
    }
    __syncthreads();
    for (int t = threadIdx.x; t < NG * HD; t += blockDim.x)
        if (sp[t] != 0.f) atomicAdd(&pool[t], sp[t]);
}

// out[g][o] = bout[o] + sum_k poolN[g][k]/cntN[g] * Wout[k][o] + poolE[g][k]/cntE[g] * Wout[64+k][o]
__global__ void final_kernel(const float* __restrict__ poolN,
                             const float* __restrict__ poolE,
                             const float* __restrict__ cntBN,
                             const float* __restrict__ cntBE,
                             const float* __restrict__ Wout,
                             const float* __restrict__ bout,
                             float* __restrict__ out) {
    int i = blockIdx.x * blockDim.x + threadIdx.x;
    if (i >= NG * 32) return;
    int g = i >> 5, o = i & 31;
    float invN = 1.f / fmaxf(cntBN[g], 1.f);
    float invE = 1.f / fmaxf(cntBE[g], 1.f);
    float s = bout[o];
#pragma unroll 8
    for (int k = 0; k < HD; k++) s += poolN[g * HD + k] * invN * Wout[k * 32 + o];
#pragma unroll 8
    for (int k = 0; k < HD; k++) s += poolE[g * HD + k] * invE * Wout[(HD + k) * 32 + o];
    out[i] = s;
}

extern "C" void kernel_launch(void* const* d_in, const int* in_sizes, int n_in,
                              void* d_out, int out_size, void* d_ws, size_t ws_size,
                              hipStream_t stream) {
    const float* node_x = (const float*)d_in[0];
    const float* edge_x = (const float*)d_in[1];
    const int* n2e_src = (const int*)d_in[2];
    const int* n2e_dst = (const int*)d_in[3];
    const int* e2n_src = (const int*)d_in[4];
    const int* e2n_dst = (const int*)d_in[5];
    const int* node_batch = (const int*)d_in[6];
    const int* edge_batch = (const int*)d_in[7];
    const float* Wn = (const float*)d_in[8];
    const float* bn = (const float*)d_in[9];
    const float* We = (const float*)d_in[10];
    const float* be = (const float*)d_in[11];
    const float* W1l_n2e = (const float*)d_in[12];
    const float* b1l_n2e = (const float*)d_in[13];
    const float* W1r_n2e = (const float*)d_in[14];
    const float* W1l_e2n = (const float*)d_in[15];
    const float* b1l_e2n = (const float*)d_in[16];
    const float* W1r_e2n = (const float*)d_in[17];
    const float* W2l_n2e = (const float*)d_in[18];
    const float* b2l_n2e = (const float*)d_in[19];
    const float* W2r_n2e = (const float*)d_in[20];
    const float* W2l_e2n = (const float*)d_in[21];
    const float* b2l_e2n = (const float*)d_in[22];
    const float* W2r_e2n = (const float*)d_in[23];
    const float* Wout = (const float*)d_in[24];
    const float* bout = (const float*)d_in[25];
    float* out = (float*)d_out;

    // ---- workspace layout (floats) ----
    float* ws = (float*)d_ws;
    float* xn   = ws;                     // 6.4M  (also xn2 later)
    float* xe   = xn + N_NODES * HD;      // 1.6M  (also xe2 later)
    float* xe1  = xe + N_HEDGES * HD;     // 1.6M
    float* xn1  = xe1 + N_HEDGES * HD;    // 6.4M
    float* aggE = xn1 + N_NODES * HD;     // 1.6M
    float* aggN = aggE + N_HEDGES * HD;   // 6.4M
    float* cnt_e = aggN + N_NODES * HD;   // 25000
    float* cnt_n = cnt_e + N_HEDGES;      // 100000
    float* poolN = cnt_n + N_NODES;       // 4096
    float* poolE = poolN + NG * HD;       // 4096
    float* cntBN = poolE + NG * HD;       // 64
    float* cntBE = cntBN + NG;            // 64

    const int B = 256;
    const int gridZ = 2048;       // grid-stride zero/scatter/combine
    const int gridScatter = 4096; // 64M work items

    // counts (zero the whole small-stats region in one shot: cnt_e..cntBE contiguous)
    int statsN = N_HEDGES + N_NODES + 2 * NG * HD + 2 * NG;
    zero_f32<<<512, B, 0, stream>>>(cnt_e, statsN);
    count_kernel<<<(N_EDGES + B - 1) / B, B, 0, stream>>>(n2e_dst, e2n_dst, cnt_e, cnt_n);
    batch_count_kernel<<<(N_NODES + B - 1) / B, B, 0, stream>>>(node_batch, edge_batch, cntBN, cntBE);

    // encoders
    encode_nodes<<<(N_NODES * HD + B - 1) / B, B, 0, stream>>>(node_x, Wn, bn, xn);
    encode_edges<<<(N_HEDGES * HD + B - 1) / B, B, 0, stream>>>(edge_x, We, be, xe);

    // ---- layer 1: n2e (nodes -> hyperedges) ----
    zero_f32<<<gridZ, B, 0, stream>>>(aggE, N_HEDGES * HD);
    scatter_add<<<gridScatter, B, 0, stream>>>(xn, n2e_src, n2e_dst, aggE);
    sage_combine<<<gridZ, B, 0, stream>>>(aggE, cnt_e, xe, W1l_n2e, b1l_n2e, W1r_n2e, xe1, N_HEDGES);

    // ---- layer 1: e2n (hyperedges -> nodes) ----
    zero_f32<<<gridZ, B, 0, stream>>>(aggN, N_NODES * HD);
    scatter_add<<<gridScatter, B, 0, stream>>>(xe, e2n_src, e2n_dst, aggN);
    sage_combine<<<gridZ, B, 0, stream>>>(aggN, cnt_n, xn, W1l_e2n, b1l_e2n, W1r_e2n, xn1, N_NODES);

    // ---- layer 2: n2e ----
    zero_f32<<<gridZ, B, 0, stream>>>(aggE, N_HEDGES * HD);
    scatter_add<<<gridScatter, B, 0, stream>>>(xn1, n2e_src, n2e_dst, aggE);
    sage_combine<<<gridZ, B, 0, stream>>>(aggE, cnt_e, xe1, W2l_n2e, b2l_n2e, W2r_n2e, xe /*xe2*/, N_HEDGES);

    // ---- layer 2: e2n ----
    zero_f32<<<gridZ, B, 0, stream>>>(aggN, N_NODES * HD);
    scatter_add<<<gridScatter, B, 0, stream>>>(xe1, e2n_src, e2n_dst, aggN);
    sage_combine<<<gridZ, B, 0, stream>>>(aggN, cnt_n, xn1, W2l_e2n, b2l_e2n, W2r_e2n, xn /*xn2*/, N_NODES);

    // ---- pooling ----
    pool_kernel<<<128, B, 0, stream>>>(xn /*xn2*/, node_batch, poolN, N_NODES);
    pool_kernel<<<64, B, 0, stream>>>(xe /*xe2*/, edge_batch, poolE, N_HEDGES);

    // ---- readout ----
    final_kernel<<<(NG * 32 + B - 1) / B, B, 0, stream>>>(poolN, poolE, cntBN, cntBE, Wout, bout, out);
}

// Round 2
// 1305.726 us; speedup vs baseline: 1.5485x; 1.5485x over previous
//
#include <hip/hip_runtime.h>

#define N_NODES 100000
#define N_HEDGES 25000
#define N_EDGES 1000000
#define NG 64
#define HD 64

// ---------------- zero utilities ----------------
__global__ void zero_f32(float* p, int n) {
    int i = blockIdx.x * blockDim.x + threadIdx.x;
    int stride = gridDim.x * blockDim.x;
    for (; i < n; i += stride) p[i] = 0.f;
}
__global__ void zero_i32(int* p, int n) {
    int i = blockIdx.x * blockDim.x + threadIdx.x;
    int stride = gridDim.x * blockDim.x;
    for (; i < n; i += stride) p[i] = 0;
}

// ---------------- CSR build ----------------
__global__ void count_int(const int* __restrict__ n2e_dst,
                          const int* __restrict__ e2n_dst,
                          int* __restrict__ cntE, int* __restrict__ cntN) {
    int i = blockIdx.x * blockDim.x + threadIdx.x;
    if (i < N_EDGES) {
        atomicAdd(&cntE[n2e_dst[i]], 1);
        atomicAdd(&cntN[e2n_dst[i]], 1);
    }
}

#define SCAN_B 256
#define SCAN_E 4
#define SCAN_TILE 1024
__global__ void scan_part(const int* __restrict__ in, int* __restrict__ out,
                          int* __restrict__ bsums, int n) {
    __shared__ int lds[SCAN_B];
    int base = blockIdx.x * SCAN_TILE;
    int t = threadIdx.x;
    int v[SCAN_E];
    int s = 0;
#pragma unroll
    for (int e = 0; e < SCAN_E; e++) {
        int idx = base + t * SCAN_E + e;
        v[e] = (idx < n) ? in[idx] : 0;
        s += v[e];
    }
    lds[t] = s;
    __syncthreads();
    for (int off = 1; off < SCAN_B; off <<= 1) {
        int x = (t >= off) ? lds[t - off] : 0;
        __syncthreads();
        lds[t] += x;
        __syncthreads();
    }
    int excl = (t > 0) ? lds[t - 1] : 0;
    if (t == SCAN_B - 1) bsums[blockIdx.x] = lds[t];
    int run = excl;
#pragma unroll
    for (int e = 0; e < SCAN_E; e++) {
        int idx = base + t * SCAN_E + e;
        if (idx < n) out[idx] = run;
        run += v[e];
    }
}
__global__ void scan_top(int* bsums, int nb) {
    if (threadIdx.x == 0 && blockIdx.x == 0) {
        int run = 0;
        for (int b = 0; b < nb; b++) { int x = bsums[b]; bsums[b] = run; run += x; }
    }
}
__global__ void scan_add(int* out, const int* __restrict__ bsums, int n) {
    int i = blockIdx.x * blockDim.x + threadIdx.x;
    if (i < n) out[i] += bsums[i >> 10];
}

__global__ void fill_csr(const int* __restrict__ n2e_src, const int* __restrict__ n2e_dst,
                         const int* __restrict__ e2n_src, const int* __restrict__ e2n_dst,
                         const int* __restrict__ offE, const int* __restrict__ offN,
                         int* __restrict__ curE, int* __restrict__ curN,
                         int* __restrict__ srtE, int* __restrict__ srtN) {
    int i = blockIdx.x * blockDim.x + threadIdx.x;
    if (i < N_EDGES) {
        int d = n2e_dst[i];
        int p = atomicAdd(&curE[d], 1);
        srtE[offE[d] + p] = n2e_src[i];
        int d2 = e2n_dst[i];
        int p2 = atomicAdd(&curN[d2], 1);
        srtN[offN[d2] + p2] = e2n_src[i];
    }
}

// ---------------- encoders ----------------
__global__ void encode_nodes(const float* __restrict__ node_x,
                             const float* __restrict__ Wn,
                             const float* __restrict__ bn,
                             float* __restrict__ xn) {
    int i = blockIdx.x * blockDim.x + threadIdx.x;
    if (i >= N_NODES * HD) return;
    int node = i >> 6, h = i & 63;
    float v = node_x[node] * Wn[h] + bn[h];
    xn[i] = v > 0.f ? v : 0.f;
}
__global__ void encode_edges(const float* __restrict__ edge_x,
                             const float* __restrict__ We,
                             const float* __restrict__ be,
                             float* __restrict__ xe) {
    int i = blockIdx.x * blockDim.x + threadIdx.x;
    if (i >= N_HEDGES * HD) return;
    int e = i >> 6, h = i & 63;
    float v = edge_x[2 * e] * We[h] + edge_x[2 * e + 1] * We[HD + h] + be[h];
    xe[i] = v > 0.f ? v : 0.f;
}

// ---------------- fused SAGE layer: gather-mean + agg@Wl + bl + xdst@Wr, relu ----------------
// one wave per dst row; lane = feature index
__global__ __launch_bounds__(256) void sage_fused(
    const float* __restrict__ xsrc, const float* __restrict__ xdst,
    const int* __restrict__ off, const int* __restrict__ cnt, const int* __restrict__ srt,
    const float* __restrict__ Wl, const float* __restrict__ bl, const float* __restrict__ Wr,
    float* __restrict__ out, int rows) {
    __shared__ float sWl[HD * HD];
    __shared__ float sWr[HD * HD];
    for (int t = threadIdx.x; t < HD * HD; t += blockDim.x) {
        sWl[t] = Wl[t];
        sWr[t] = Wr[t];
    }
    __syncthreads();
    int lane = threadIdx.x & 63;
    int wid = blockIdx.x * (blockDim.x >> 6) + (threadIdx.x >> 6);
    int nw = gridDim.x * (blockDim.x >> 6);
    float blv = bl[lane];
    for (int r = wid; r < rows; r += nw) {
        int lo = off[r], deg = cnt[r];
        float acc = 0.f;
        for (int j0 = 0; j0 < deg; j0 += 64) {
            int m = deg - j0;
            if (m > 64) m = 64;
            int id = (j0 + lane < deg) ? srt[lo + j0 + lane] : 0;
            for (int jj = 0; jj < m; ++jj) {
                int s = __shfl(id, jj);
                acc += xsrc[(long)s * HD + lane];
            }
        }
        acc *= 1.f / (float)(deg > 1 ? deg : 1);
        float xd = xdst[(long)r * HD + lane];
        float sum = blv;
#pragma unroll
        for (int k = 0; k < HD; k++) {
            float a = __shfl(acc, k);
            float x = __shfl(xd, k);
            sum += a * sWl[k * HD + lane] + x * sWr[k * HD + lane];
        }
        out[(long)r * HD + lane] = sum > 0.f ? sum : 0.f;
    }
}

// ---------------- pooling ----------------
__global__ void pool_kernel(const float* __restrict__ x,
                            const int* __restrict__ batch,
                            float* __restrict__ pool, int rows) {
    __shared__ float sp[NG * HD];  // 16 KB
    for (int t = threadIdx.x; t < NG * HD; t += blockDim.x) sp[t] = 0.f;
    __syncthreads();
    long total = (long)rows * HD;
    long stride = (long)gridDim.x * blockDim.x;
    for (long i = (long)blockIdx.x * blockDim.x + threadIdx.x; i < total; i += stride) {
        int r = (int)(i >> 6), h = (int)(i & 63);
        atomicAdd(&sp[batch[r] * HD + h], x[i]);
    }
    __syncthreads();
    for (int t = threadIdx.x; t < NG * HD; t += blockDim.x)
        if (sp[t] != 0.f) atomicAdd(&pool[t], sp[t]);
}

// batch counts via binary search over the sorted batch arrays
__global__ void batch_counts_bs(const int* __restrict__ node_batch,
                                const int* __restrict__ edge_batch,
                                float* __restrict__ cntBN, float* __restrict__ cntBE) {
    int t = threadIdx.x;  // 128 threads
    if (t >= 128) return;
    const int* arr = (t < 64) ? node_batch : edge_batch;
    int n = (t < 64) ? N_NODES : N_HEDGES;
    int g = t & 63;
    int lo1 = 0, hi1 = n;
    while (lo1 < hi1) { int mid = (lo1 + hi1) >> 1; if (arr[mid] < g) lo1 = mid + 1; else hi1 = mid; }
    int lo2 = 0, hi2 = n;
    while (lo2 < hi2) { int mid = (lo2 + hi2) >> 1; if (arr[mid] < g + 1) lo2 = mid + 1; else hi2 = mid; }
    float c = (float)(lo2 - lo1);
    if (t < 64) cntBN[g] = c; else cntBE[g] = c;
}

// out[g][o] = bout[o] + sum_k poolN[g][k]/cntN[g]*Wout[k][o] + poolE[g][k]/cntE[g]*Wout[64+k][o]
__global__ void final_kernel(const float* __restrict__ poolN,
                             const float* __restrict__ poolE,
                             const float* __restrict__ cntBN,
                             const float* __restrict__ cntBE,
                             const float* __restrict__ Wout,
                             const float* __restrict__ bout,
                             float* __restrict__ out) {
    int i = blockIdx.x * blockDim.x + threadIdx.x;
    if (i >= NG * 32) return;
    int g = i >> 5, o = i & 31;
    float invN = 1.f / fmaxf(cntBN[g], 1.f);
    float invE = 1.f / fmaxf(cntBE[g], 1.f);
    float s = bout[o];
#pragma unroll 8
    for (int k = 0; k < HD; k++) s += poolN[g * HD + k] * invN * Wout[k * 32 + o];
#pragma unroll 8
    for (int k = 0; k < HD; k++) s += poolE[g * HD + k] * invE * Wout[(HD + k) * 32 + o];
    out[i] = s;
}

extern "C" void kernel_launch(void* const* d_in, const int* in_sizes, int n_in,
                              void* d_out, int out_size, void* d_ws, size_t ws_size,
                              hipStream_t stream) {
    const float* node_x = (const float*)d_in[0];
    const float* edge_x = (const float*)d_in[1];
    const int* n2e_src = (const int*)d_in[2];
    const int* n2e_dst = (const int*)d_in[3];
    const int* e2n_src = (const int*)d_in[4];
    const int* e2n_dst = (const int*)d_in[5];
    const int* node_batch = (const int*)d_in[6];
    const int* edge_batch = (const int*)d_in[7];
    const float* Wn = (const float*)d_in[8];
    const float* bn = (const float*)d_in[9];
    const float* We = (const float*)d_in[10];
    const float* be = (const float*)d_in[11];
    const float* W1l_n2e = (const float*)d_in[12];
    const float* b1l_n2e = (const float*)d_in[13];
    const float* W1r_n2e = (const float*)d_in[14];
    const float* W1l_e2n = (const float*)d_in[15];
    const float* b1l_e2n = (const float*)d_in[16];
    const float* W1r_e2n = (const float*)d_in[17];
    const float* W2l_n2e = (const float*)d_in[18];
    const float* b2l_n2e = (const float*)d_in[19];
    const float* W2r_n2e = (const float*)d_in[20];
    const float* W2l_e2n = (const float*)d_in[21];
    const float* b2l_e2n = (const float*)d_in[22];
    const float* W2r_e2n = (const float*)d_in[23];
    const float* Wout = (const float*)d_in[24];
    const float* bout = (const float*)d_in[25];
    float* out = (float*)d_out;

    // ---- workspace layout ----
    float* ws = (float*)d_ws;
    float* xn = ws;                      // 6.4M floats (also xn2)
    float* xe = xn + N_NODES * HD;       // 1.6M (also xe2)
    float* xe1 = xe + N_HEDGES * HD;     // 1.6M
    float* xn1 = xe1 + N_HEDGES * HD;    // 6.4M
    float* poolN = xn1 + N_NODES * HD;   // 4096
    float* poolE = poolN + NG * HD;      // 4096
    float* cntBN = poolE + NG * HD;      // 64
    float* cntBE = cntBN + NG;           // 64
    int* iws = (int*)(cntBE + NG);
    int* cntE = iws;                     // 25000
    int* cntN = cntE + N_HEDGES;         // 100000
    int* curE = cntN + N_NODES;          // 25000
    int* curN = curE + N_HEDGES;         // 100000
    int* offE = curN + N_NODES;          // 25000
    int* offN = offE + N_HEDGES;         // 100000
    int* srtE = offN + N_NODES;          // 1M
    int* srtN = srtE + N_EDGES;          // 1M
    int* bsumsE = srtN + N_EDGES;        // 32
    int* bsumsN = bsumsE + 32;           // 128

    const int B = 256;

    // ---- CSR build (counts -> scan -> fill) ----
    zero_i32<<<256, B, 0, stream>>>(cntE, 2 * (N_HEDGES + N_NODES));  // cntE..curN contiguous
    count_int<<<(N_EDGES + B - 1) / B, B, 0, stream>>>(n2e_dst, e2n_dst, cntE, cntN);
    {
        int nbE = (N_HEDGES + SCAN_TILE - 1) / SCAN_TILE;  // 25
        int nbN = (N_NODES + SCAN_TILE - 1) / SCAN_TILE;   // 98
        scan_part<<<nbE, SCAN_B, 0, stream>>>(cntE, offE, bsumsE, N_HEDGES);
        scan_part<<<nbN, SCAN_B, 0, stream>>>(cntN, offN, bsumsN, N_NODES);
        scan_top<<<1, 64, 0, stream>>>(bsumsE, nbE);
        scan_top<<<1, 64, 0, stream>>>(bsumsN, nbN);
        scan_add<<<(N_HEDGES + B - 1) / B, B, 0, stream>>>(offE, bsumsE, N_HEDGES);
        scan_add<<<(N_NODES + B - 1) / B, B, 0, stream>>>(offN, bsumsN, N_NODES);
    }
    fill_csr<<<(N_EDGES + B - 1) / B, B, 0, stream>>>(n2e_src, n2e_dst, e2n_src, e2n_dst,
                                                      offE, offN, curE, curN, srtE, srtN);

    // ---- encoders ----
    encode_nodes<<<(N_NODES * HD + B - 1) / B, B, 0, stream>>>(node_x, Wn, bn, xn);
    encode_edges<<<(N_HEDGES * HD + B - 1) / B, B, 0, stream>>>(edge_x, We, be, xe);

    // ---- layer 1 ----
    sage_fused<<<1024, B, 0, stream>>>(xn, xe, offE, cntE, srtE, W1l_n2e, b1l_n2e, W1r_n2e, xe1, N_HEDGES);
    sage_fused<<<2048, B, 0, stream>>>(xe, xn, offN, cntN, srtN, W1l_e2n, b1l_e2n, W1r_e2n, xn1, N_NODES);

    // ---- layer 2 ----
    sage_fused<<<1024, B, 0, stream>>>(xn1, xe1, offE, cntE, srtE, W2l_n2e, b2l_n2e, W2r_n2e, xe /*xe2*/, N_HEDGES);
    sage_fused<<<2048, B, 0, stream>>>(xe1, xn1, offN, cntN, srtN, W2l_e2n, b2l_e2n, W2r_e2n, xn /*xn2*/, N_NODES);

    // ---- pooling ----
    zero_f32<<<64, B, 0, stream>>>(poolN, 2 * NG * HD);  // poolN+poolE contiguous
    pool_kernel<<<512, B, 0, stream>>>(xn /*xn2*/, node_batch, poolN, N_NODES);
    pool_kernel<<<256, B, 0, stream>>>(xe /*xe2*/, edge_batch, poolE, N_HEDGES);
    batch_counts_bs<<<1, 128, 0, stream>>>(node_batch, edge_batch, cntBN, cntBE);

    // ---- readout ----
    final_kernel<<<(NG * 32 + B - 1) / B, B, 0, stream>>>(poolN, poolE, cntBN, cntBE, Wout, bout, out);
}

// Round 3
// 1161.470 us; speedup vs baseline: 1.7409x; 1.1242x over previous
//
#include <hip/hip_runtime.h>

#define N_NODES 100000
#define N_HEDGES 25000
#define N_EDGES 1000000
#define NG 64
#define HD 64

typedef __attribute__((ext_vector_type(4))) float f4;

// ---------------- zero utilities ----------------
__global__ void zero_i32(int* p, int n) {
    int i = blockIdx.x * blockDim.x + threadIdx.x;
    int stride = gridDim.x * blockDim.x;
    for (; i < n; i += stride) p[i] = 0;
}
__global__ void zero_f32(float* p, int n) {
    int i = blockIdx.x * blockDim.x + threadIdx.x;
    int stride = gridDim.x * blockDim.x;
    for (; i < n; i += stride) p[i] = 0.f;
}

// ---------------- CSR build ----------------
__global__ void count_int(const int* __restrict__ n2e_dst,
                          const int* __restrict__ e2n_dst,
                          int* __restrict__ cntE, int* __restrict__ cntN) {
    int i = blockIdx.x * blockDim.x + threadIdx.x;
    if (i < N_EDGES) {
        atomicAdd(&cntE[n2e_dst[i]], 1);
        atomicAdd(&cntN[e2n_dst[i]], 1);
    }
}

#define SCAN_B 256
#define SCAN_E 4
#define SCAN_TILE 1024
__global__ void scan_part(const int* __restrict__ in, int* __restrict__ out,
                          int* __restrict__ bsums, int n) {
    __shared__ int lds[SCAN_B];
    int base = blockIdx.x * SCAN_TILE;
    int t = threadIdx.x;
    int v[SCAN_E];
    int s = 0;
#pragma unroll
    for (int e = 0; e < SCAN_E; e++) {
        int idx = base + t * SCAN_E + e;
        v[e] = (idx < n) ? in[idx] : 0;
        s += v[e];
    }
    lds[t] = s;
    __syncthreads();
    for (int off = 1; off < SCAN_B; off <<= 1) {
        int x = (t >= off) ? lds[t - off] : 0;
        __syncthreads();
        lds[t] += x;
        __syncthreads();
    }
    int excl = (t > 0) ? lds[t - 1] : 0;
    if (t == SCAN_B - 1) bsums[blockIdx.x] = lds[t];
    int run = excl;
#pragma unroll
    for (int e = 0; e < SCAN_E; e++) {
        int idx = base + t * SCAN_E + e;
        if (idx < n) out[idx] = run;
        run += v[e];
    }
}
// parallel top-level exclusive scan (nb <= 128), one block of 128 threads
__global__ void scan_top(int* bsums, int nb) {
    __shared__ int s[128];
    int t = threadIdx.x;
    int v = (t < nb) ? bsums[t] : 0;
    s[t] = v;
    __syncthreads();
    for (int off = 1; off < 128; off <<= 1) {
        int x = (t >= off) ? s[t - off] : 0;
        __syncthreads();
        s[t] += x;
        __syncthreads();
    }
    if (t < nb) bsums[t] = s[t] - v;  // exclusive
}
__global__ void scan_add(int* out, const int* __restrict__ bsums, int n) {
    int i = blockIdx.x * blockDim.x + threadIdx.x;
    if (i < n) out[i] += bsums[i >> 10];
}

__global__ void fill_csr(const int* __restrict__ n2e_src, const int* __restrict__ n2e_dst,
                         const int* __restrict__ e2n_src, const int* __restrict__ e2n_dst,
                         const int* __restrict__ offE, const int* __restrict__ offN,
                         int* __restrict__ curE, int* __restrict__ curN,
                         int* __restrict__ srtE, int* __restrict__ srtN) {
    int i = blockIdx.x * blockDim.x + threadIdx.x;
    if (i < N_EDGES) {
        int d = n2e_dst[i];
        int p = atomicAdd(&curE[d], 1);
        srtE[offE[d] + p] = n2e_src[i];
        int d2 = e2n_dst[i];
        int p2 = atomicAdd(&curN[d2], 1);
        srtN[offN[d2] + p2] = e2n_src[i];
    }
}

// ---------------- encoders ----------------
__global__ void encode_nodes(const float* __restrict__ node_x,
                             const float* __restrict__ Wn,
                             const float* __restrict__ bn,
                             float* __restrict__ xn) {
    int i = blockIdx.x * blockDim.x + threadIdx.x;
    if (i >= N_NODES * HD) return;
    int node = i >> 6, h = i & 63;
    float v = node_x[node] * Wn[h] + bn[h];
    xn[i] = v > 0.f ? v : 0.f;
}
__global__ void encode_edges(const float* __restrict__ edge_x,
                             const float* __restrict__ We,
                             const float* __restrict__ be,
                             float* __restrict__ xe) {
    int i = blockIdx.x * blockDim.x + threadIdx.x;
    if (i >= N_HEDGES * HD) return;
    int e = i >> 6, h = i & 63;
    float v = edge_x[2 * e] * We[h] + edge_x[2 * e + 1] * We[HD + h] + be[h];
    xe[i] = v > 0.f ? v : 0.f;
}

// ---------------- fused SAGE tile kernel ----------------
// Block = 64 dst rows. Phase 1: 4 waves gather-mean 16 rows each into LDS A-tile
// (lane = feature). Phase 2: 16x16-thread register-tiled GEMM (4x4 per thread):
//   out = relu(A @ Wl + bl + X @ Wr), W staged in 32-k halves (LDS budget 50 KB
//   -> 3 blocks/CU).
__global__ __launch_bounds__(256) void sage_tile(
    const float* __restrict__ xsrc, const float* __restrict__ xdst,
    const int* __restrict__ off, const int* __restrict__ cnt, const int* __restrict__ srt,
    const float* __restrict__ Wl, const float* __restrict__ bl, const float* __restrict__ Wr,
    float* __restrict__ out, int rows) {
    __shared__ float sW0[32 * 64];  // Wl half  (8 KB)
    __shared__ float sW1[32 * 64];  // Wr half  (8 KB)
    __shared__ float sA[64][68];    // mean-agg tile (17 KB, pad 4 keeps 16B align)
    __shared__ float sX[64][68];    // xdst tile (17 KB)

    int t = threadIdx.x;
    int lane = t & 63, wv = t >> 6;
    int row0 = blockIdx.x * 64;

    // stage xdst tile (thread-linear, coalesced f4)
    {
        int r = t >> 2, c0s = (t & 3) * 16;
        int gr = row0 + r;
        if (gr < rows) {
            const f4* gx = (const f4*)(xdst + (long)gr * HD + c0s);
            f4* lx = (f4*)&sX[r][c0s];
#pragma unroll
            for (int q = 0; q < 4; q++) lx[q] = gx[q];
        }
    }

    // gather-mean: wave wv handles rows wv*16 .. wv*16+15
    for (int i = 0; i < 16; i++) {
        int rr = wv * 16 + i;
        int r = row0 + rr;
        if (r >= rows) break;
        int lo = off[r], deg = cnt[r];
        float acc = 0.f;
        for (int j0 = 0; j0 < deg; j0 += 64) {
            int m = deg - j0;
            if (m > 64) m = 64;
            int id = (j0 + lane < deg) ? srt[lo + j0 + lane] : 0;
            for (int jj = 0; jj < m; ++jj) {
                int s = __shfl(id, jj);
                acc += xsrc[(long)s * HD + lane];
            }
        }
        sA[rr][lane] = acc / (float)(deg > 1 ? deg : 1);
    }

    // register-tiled GEMM: thread (tr,tc) owns rows m0..m0+3, cols c0..c0+3
    int tc = t & 15, tr = t >> 4;
    int c0 = tc * 4, m0 = tr * 4;
    f4 acc[4];
    f4 blv = *(const f4*)(bl + c0);
#pragma unroll
    for (int i = 0; i < 4; i++) acc[i] = blv;

    for (int half = 0; half < 2; half++) {
        __syncthreads();  // half 0: gather/stage barrier; half 1: protect sW reuse
        for (int i = t; i < 32 * 64; i += 256) {
            sW0[i] = Wl[half * 2048 + i];
            sW1[i] = Wr[half * 2048 + i];
        }
        __syncthreads();
#pragma unroll
        for (int kq = 0; kq < 8; kq++) {
            int k0 = kq * 4;
            int ka = half * 32 + k0;
            f4 wl[4], wr[4];
#pragma unroll
            for (int kk = 0; kk < 4; kk++) {
                wl[kk] = *(const f4*)&sW0[(k0 + kk) * 64 + c0];
                wr[kk] = *(const f4*)&sW1[(k0 + kk) * 64 + c0];
            }
#pragma unroll
            for (int i = 0; i < 4; i++) {
                f4 a = *(const f4*)&sA[m0 + i][ka];
                f4 x = *(const f4*)&sX[m0 + i][ka];
#pragma unroll
                for (int kk = 0; kk < 4; kk++)
                    acc[i] += a[kk] * wl[kk] + x[kk] * wr[kk];
            }
        }
    }

#pragma unroll
    for (int i = 0; i < 4; i++) {
        int gr = row0 + m0 + i;
        if (gr < rows) {
            f4 v = acc[i];
#pragma unroll
            for (int j = 0; j < 4; j++) v[j] = fmaxf(v[j], 0.f);
            *(f4*)(out + (long)gr * HD + c0) = v;
        }
    }
}

// ---------------- pooling ----------------
__global__ void pool_kernel(const float* __restrict__ x,
                            const int* __restrict__ batch,
                            float* __restrict__ pool, int rows) {
    __shared__ float sp[NG * HD];  // 16 KB
    for (int t = threadIdx.x; t < NG * HD; t += blockDim.x) sp[t] = 0.f;
    __syncthreads();
    long total = (long)rows * HD;
    long stride = (long)gridDim.x * blockDim.x;
    for (long i = (long)blockIdx.x * blockDim.x + threadIdx.x; i < total; i += stride) {
        int r = (int)(i >> 6), h = (int)(i & 63);
        atomicAdd(&sp[batch[r] * HD + h], x[i]);
    }
    __syncthreads();
    for (int t = threadIdx.x; t < NG * HD; t += blockDim.x)
        if (sp[t] != 0.f) atomicAdd(&pool[t], sp[t]);
}

// batch counts via binary search (sorted batch arrays)
__global__ void batch_counts_bs(const int* __restrict__ node_batch,
                                const int* __restrict__ edge_batch,
                                float* __restrict__ cntBN, float* __restrict__ cntBE) {
    int t = threadIdx.x;
    if (t >= 128) return;
    const int* arr = (t < 64) ? node_batch : edge_batch;
    int n = (t < 64) ? N_NODES : N_HEDGES;
    int g = t & 63;
    int lo1 = 0, hi1 = n;
    while (lo1 < hi1) { int mid = (lo1 + hi1) >> 1; if (arr[mid] < g) lo1 = mid + 1; else hi1 = mid; }
    int lo2 = 0, hi2 = n;
    while (lo2 < hi2) { int mid = (lo2 + hi2) >> 1; if (arr[mid] < g + 1) lo2 = mid + 1; else hi2 = mid; }
    float c = (float)(lo2 - lo1);
    if (t < 64) cntBN[g] = c; else cntBE[g] = c;
}

__global__ void final_kernel(const float* __restrict__ poolN,
                             const float* __restrict__ poolE,
                             const float* __restrict__ cntBN,
                             const float* __restrict__ cntBE,
                             const float* __restrict__ Wout,
                             const float* __restrict__ bout,
                             float* __restrict__ out) {
    int i = blockIdx.x * blockDim.x + threadIdx.x;
    if (i >= NG * 32) return;
    int g = i >> 5, o = i & 31;
    float invN = 1.f / fmaxf(cntBN[g], 1.f);
    float invE = 1.f / fmaxf(cntBE[g], 1.f);
    float s = bout[o];
#pragma unroll 8
    for (int k = 0; k < HD; k++) s += poolN[g * HD + k] * invN * Wout[k * 32 + o];
#pragma unroll 8
    for (int k = 0; k < HD; k++) s += poolE[g * HD + k] * invE * Wout[(HD + k) * 32 + o];
    out[i] = s;
}

extern "C" void kernel_launch(void* const* d_in, const int* in_sizes, int n_in,
                              void* d_out, int out_size, void* d_ws, size_t ws_size,
                              hipStream_t stream) {
    const float* node_x = (const float*)d_in[0];
    const float* edge_x = (const float*)d_in[1];
    const int* n2e_src = (const int*)d_in[2];
    const int* n2e_dst = (const int*)d_in[3];
    const int* e2n_src = (const int*)d_in[4];
    const int* e2n_dst = (const int*)d_in[5];
    const int* node_batch = (const int*)d_in[6];
    const int* edge_batch = (const int*)d_in[7];
    const float* Wn = (const float*)d_in[8];
    const float* bn = (const float*)d_in[9];
    const float* We = (const float*)d_in[10];
    const float* be = (const float*)d_in[11];
    const float* W1l_n2e = (const float*)d_in[12];
    const float* b1l_n2e = (const float*)d_in[13];
    const float* W1r_n2e = (const float*)d_in[14];
    const float* W1l_e2n = (const float*)d_in[15];
    const float* b1l_e2n = (const float*)d_in[16];
    const float* W1r_e2n = (const float*)d_in[17];
    const float* W2l_n2e = (const float*)d_in[18];
    const float* b2l_n2e = (const float*)d_in[19];
    const float* W2r_n2e = (const float*)d_in[20];
    const float* W2l_e2n = (const float*)d_in[21];
    const float* b2l_e2n = (const float*)d_in[22];
    const float* W2r_e2n = (const float*)d_in[23];
    const float* Wout = (const float*)d_in[24];
    const float* bout = (const float*)d_in[25];
    float* out = (float*)d_out;

    // ---- workspace layout ----
    float* ws = (float*)d_ws;
    float* xn = ws;                      // 6.4M floats (also xn2)
    float* xe = xn + N_NODES * HD;       // 1.6M (also xe2)
    float* xe1 = xe + N_HEDGES * HD;     // 1.6M
    float* xn1 = xe1 + N_HEDGES * HD;    // 6.4M
    float* poolN = xn1 + N_NODES * HD;   // 4096
    float* poolE = poolN + NG * HD;      // 4096
    float* cntBN = poolE + NG * HD;      // 64
    float* cntBE = cntBN + NG;           // 64
    int* iws = (int*)(cntBE + NG);
    int* cntE = iws;                     // 25000
    int* cntN = cntE + N_HEDGES;         // 100000
    int* curE = cntN + N_NODES;          // 25000
    int* curN = curE + N_HEDGES;         // 100000
    int* offE = curN + N_NODES;          // 25000
    int* offN = offE + N_HEDGES;         // 100000
    int* srtE = offN + N_NODES;          // 1M
    int* srtN = srtE + N_EDGES;          // 1M
    int* bsumsE = srtN + N_EDGES;        // 32
    int* bsumsN = bsumsE + 32;           // 128

    const int B = 256;

    // ---- CSR build ----
    zero_i32<<<256, B, 0, stream>>>(cntE, 2 * (N_HEDGES + N_NODES));  // cntE..curN contiguous
    count_int<<<(N_EDGES + B - 1) / B, B, 0, stream>>>(n2e_dst, e2n_dst, cntE, cntN);
    {
        int nbE = (N_HEDGES + SCAN_TILE - 1) / SCAN_TILE;  // 25
        int nbN = (N_NODES + SCAN_TILE - 1) / SCAN_TILE;   // 98
        scan_part<<<nbE, SCAN_B, 0, stream>>>(cntE, offE, bsumsE, N_HEDGES);
        scan_part<<<nbN, SCAN_B, 0, stream>>>(cntN, offN, bsumsN, N_NODES);
        scan_top<<<1, 128, 0, stream>>>(bsumsE, nbE);
        scan_top<<<1, 128, 0, stream>>>(bsumsN, nbN);
        scan_add<<<(N_HEDGES + B - 1) / B, B, 0, stream>>>(offE, bsumsE, N_HEDGES);
        scan_add<<<(N_NODES + B - 1) / B, B, 0, stream>>>(offN, bsumsN, N_NODES);
    }
    fill_csr<<<(N_EDGES + B - 1) / B, B, 0, stream>>>(n2e_src, n2e_dst, e2n_src, e2n_dst,
                                                      offE, offN, curE, curN, srtE, srtN);

    // ---- encoders ----
    encode_nodes<<<(N_NODES * HD + B - 1) / B, B, 0, stream>>>(node_x, Wn, bn, xn);
    encode_edges<<<(N_HEDGES * HD + B - 1) / B, B, 0, stream>>>(edge_x, We, be, xe);

    int gbE = (N_HEDGES + 63) / 64;  // 391
    int gbN = (N_NODES + 63) / 64;   // 1563

    // ---- layer 1 ----
    sage_tile<<<gbE, B, 0, stream>>>(xn, xe, offE, cntE, srtE, W1l_n2e, b1l_n2e, W1r_n2e, xe1, N_HEDGES);
    sage_tile<<<gbN, B, 0, stream>>>(xe, xn, offN, cntN, srtN, W1l_e2n, b1l_e2n, W1r_e2n, xn1, N_NODES);

    // ---- layer 2 ----
    sage_tile<<<gbE, B, 0, stream>>>(xn1, xe1, offE, cntE, srtE, W2l_n2e, b2l_n2e, W2r_n2e, xe /*xe2*/, N_HEDGES);
    sage_tile<<<gbN, B, 0, stream>>>(xe1, xn1, offN, cntN, srtN, W2l_e2n, b2l_e2n, W2r_e2n, xn /*xn2*/, N_NODES);

    // ---- pooling ----
    zero_f32<<<64, B, 0, stream>>>(poolN, 2 * NG * HD);  // poolN+poolE contiguous
    pool_kernel<<<512, B, 0, stream>>>(xn /*xn2*/, node_batch, poolN, N_NODES);
    pool_kernel<<<256, B, 0, stream>>>(xe /*xe2*/, edge_batch, poolE, N_HEDGES);
    batch_counts_bs<<<1, 128, 0, stream>>>(node_batch, edge_batch, cntBN, cntBE);

    // ---- readout ----
    final_kernel<<<(NG * 32 + B - 1) / B, B, 0, stream>>>(poolN, poolE, cntBN, cntBE, Wout, bout, out);
}

// Round 4
// 656.677 us; speedup vs baseline: 3.0791x; 1.7687x over previous
//
#include <hip/hip_runtime.h>

#define N_NODES 100000
#define N_HEDGES 25000
#define N_EDGES 1000000
#define NG 64
#define HD 64

typedef __attribute__((ext_vector_type(4))) float f4;

// ---------------- zero utilities ----------------
__global__ void zero_i32(int* p, int n) {
    int i = blockIdx.x * blockDim.x + threadIdx.x;
    int stride = gridDim.x * blockDim.x;
    for (; i < n; i += stride) p[i] = 0;
}
__global__ void zero_f32(float* p, int n) {
    int i = blockIdx.x * blockDim.x + threadIdx.x;
    int stride = gridDim.x * blockDim.x;
    for (; i < n; i += stride) p[i] = 0.f;
}

// ---------------- CSR build ----------------
__global__ void count_int(const int* __restrict__ n2e_dst,
                          const int* __restrict__ e2n_dst,
                          int* __restrict__ cntE, int* __restrict__ cntN) {
    int i = blockIdx.x * blockDim.x + threadIdx.x;
    if (i < N_EDGES) {
        atomicAdd(&cntE[n2e_dst[i]], 1);
        atomicAdd(&cntN[e2n_dst[i]], 1);
    }
}

#define SCAN_B 256
#define SCAN_E 4
#define SCAN_TILE 1024
__global__ void scan_part(const int* __restrict__ in, int* __restrict__ out,
                          int* __restrict__ bsums, int n) {
    __shared__ int lds[SCAN_B];
    int base = blockIdx.x * SCAN_TILE;
    int t = threadIdx.x;
    int v[SCAN_E];
    int s = 0;
#pragma unroll
    for (int e = 0; e < SCAN_E; e++) {
        int idx = base + t * SCAN_E + e;
        v[e] = (idx < n) ? in[idx] : 0;
        s += v[e];
    }
    lds[t] = s;
    __syncthreads();
    for (int off = 1; off < SCAN_B; off <<= 1) {
        int x = (t >= off) ? lds[t - off] : 0;
        __syncthreads();
        lds[t] += x;
        __syncthreads();
    }
    int excl = (t > 0) ? lds[t - 1] : 0;
    if (t == SCAN_B - 1) bsums[blockIdx.x] = lds[t];
    int run = excl;
#pragma unroll
    for (int e = 0; e < SCAN_E; e++) {
        int idx = base + t * SCAN_E + e;
        if (idx < n) out[idx] = run;
        run += v[e];
    }
}
__global__ void scan_top(int* bsums, int nb) {
    __shared__ int s[128];
    int t = threadIdx.x;
    int v = (t < nb) ? bsums[t] : 0;
    s[t] = v;
    __syncthreads();
    for (int off = 1; off < 128; off <<= 1) {
        int x = (t >= off) ? s[t - off] : 0;
        __syncthreads();
        s[t] += x;
        __syncthreads();
    }
    if (t < nb) bsums[t] = s[t] - v;  // exclusive
}
__global__ void scan_add(int* out, const int* __restrict__ bsums, int n) {
    int i = blockIdx.x * blockDim.x + threadIdx.x;
    if (i < n) out[i] += bsums[i >> 10];
}

__global__ void fill_csr(const int* __restrict__ n2e_src, const int* __restrict__ n2e_dst,
                         const int* __restrict__ e2n_src, const int* __restrict__ e2n_dst,
                         const int* __restrict__ offE, const int* __restrict__ offN,
                         int* __restrict__ curE, int* __restrict__ curN,
                         int* __restrict__ srtE, int* __restrict__ srtN) {
    int i = blockIdx.x * blockDim.x + threadIdx.x;
    if (i < N_EDGES) {
        int d = n2e_dst[i];
        int p = atomicAdd(&curE[d], 1);
        srtE[offE[d] + p] = n2e_src[i];
        int d2 = e2n_dst[i];
        int p2 = atomicAdd(&curN[d2], 1);
        srtN[offN[d2] + p2] = e2n_src[i];
    }
}

// ---------------- encoders ----------------
__global__ void encode_nodes(const float* __restrict__ node_x,
                             const float* __restrict__ Wn,
                             const float* __restrict__ bn,
                             float* __restrict__ xn) {
    int i = blockIdx.x * blockDim.x + threadIdx.x;
    if (i >= N_NODES * HD) return;
    int node = i >> 6, h = i & 63;
    float v = node_x[node] * Wn[h] + bn[h];
    xn[i] = v > 0.f ? v : 0.f;
}
__global__ void encode_edges(const float* __restrict__ edge_x,
                             const float* __restrict__ We,
                             const float* __restrict__ be,
                             float* __restrict__ xe) {
    int i = blockIdx.x * blockDim.x + threadIdx.x;
    if (i >= N_HEDGES * HD) return;
    int e = i >> 6, h = i & 63;
    float v = edge_x[2 * e] * We[h] + edge_x[2 * e + 1] * We[HD + h] + be[h];
    xe[i] = v > 0.f ? v : 0.f;
}

// ---------------- fused SAGE layer (both directions in one dispatch) ----------------
// Block = 64 dst rows. Gather: wave handles 16 rows; lanes = (4 edge-sublanes x
// 16 f4-chunks): one wave pulls 4 edges (1 KB) per load instr, 4 indep acc
// chains, butterfly-reduced at row end. GEMM: 16x16 threads, 4x4 reg tile.
__device__ __forceinline__ void sage_body(
    const float* __restrict__ xsrc, const float* __restrict__ xdst,
    const int* __restrict__ off, const int* __restrict__ cnt, const int* __restrict__ srt,
    const float* __restrict__ Wl, const float* __restrict__ bl, const float* __restrict__ Wr,
    float* __restrict__ out, int rows, int row0) {
    __shared__ float sW0[32 * 64];  // Wl half  (8 KB)
    __shared__ float sW1[32 * 64];  // Wr half  (8 KB)
    __shared__ float sA[64][68];    // mean-agg tile
    __shared__ float sX[64][68];    // xdst tile

    int t = threadIdx.x;
    int lane = t & 63, wv = t >> 6;

    // stage xdst tile (coalesced f4)
    {
        int r = t >> 2, c0s = (t & 3) * 16;
        int gr = row0 + r;
        if (gr < rows) {
            const f4* gx = (const f4*)(xdst + (long)gr * HD + c0s);
            f4* lx = (f4*)&sX[r][c0s];
#pragma unroll
            for (int q = 0; q < 4; q++) lx[q] = gx[q];
        }
    }

    // gather-mean: wave wv -> rows wv*16..+15; 4 edges in flight per load
    int esub = lane >> 4;   // 0..3: edge sublane
    int fq = lane & 15;     // f4 chunk 0..15
    for (int i = 0; i < 16; i++) {
        int rr = wv * 16 + i;
        int r = row0 + rr;
        if (r >= rows) break;
        int lo = off[r], deg = cnt[r];
        f4 acc = {0.f, 0.f, 0.f, 0.f};
        for (int j0 = 0; j0 < deg; j0 += 64) {
            int chunk = deg - j0;
            if (chunk > 64) chunk = 64;
            int idv = (j0 + lane < deg) ? srt[lo + j0 + lane] : 0;
            for (int jj = 0; jj < chunk; jj += 4) {
                int e = jj + esub;
                int s = __shfl(idv, e);
                f4 v = *(const f4*)(xsrc + (long)s * HD + fq * 4);
                if (e < chunk) acc += v;
            }
        }
#pragma unroll
        for (int c = 0; c < 4; c++) {
            acc[c] += __shfl_xor(acc[c], 16);
            acc[c] += __shfl_xor(acc[c], 32);
        }
        float invd = 1.f / (float)(deg > 1 ? deg : 1);
        if (lane < 16) {
            f4 m = acc * invd;
            *(f4*)&sA[rr][fq * 4] = m;
        }
    }

    // register-tiled GEMM
    int tc = t & 15, tr = t >> 4;
    int c0 = tc * 4, m0 = tr * 4;
    f4 acc[4];
    f4 blv = *(const f4*)(bl + c0);
#pragma unroll
    for (int i = 0; i < 4; i++) acc[i] = blv;

    for (int half = 0; half < 2; half++) {
        __syncthreads();
        for (int i = t; i < 32 * 64; i += 256) {
            sW0[i] = Wl[half * 2048 + i];
            sW1[i] = Wr[half * 2048 + i];
        }
        __syncthreads();
#pragma unroll
        for (int kq = 0; kq < 8; kq++) {
            int k0 = kq * 4;
            int ka = half * 32 + k0;
            f4 wl[4], wr[4];
#pragma unroll
            for (int kk = 0; kk < 4; kk++) {
                wl[kk] = *(const f4*)&sW0[(k0 + kk) * 64 + c0];
                wr[kk] = *(const f4*)&sW1[(k0 + kk) * 64 + c0];
            }
#pragma unroll
            for (int i = 0; i < 4; i++) {
                f4 a = *(const f4*)&sA[m0 + i][ka];
                f4 x = *(const f4*)&sX[m0 + i][ka];
#pragma unroll
                for (int kk = 0; kk < 4; kk++)
                    acc[i] += a[kk] * wl[kk] + x[kk] * wr[kk];
            }
        }
    }

#pragma unroll
    for (int i = 0; i < 4; i++) {
        int gr = row0 + m0 + i;
        if (gr < rows) {
            f4 v = acc[i];
#pragma unroll
            for (int j = 0; j < 4; j++) v[j] = fmaxf(v[j], 0.f);
            *(f4*)(out + (long)gr * HD + c0) = v;
        }
    }
}

__global__ __launch_bounds__(256) void sage_layer(
    const float* __restrict__ xnIn, const float* __restrict__ xeIn,
    const int* __restrict__ offE, const int* __restrict__ cntE, const int* __restrict__ srtE,
    const int* __restrict__ offN, const int* __restrict__ cntN, const int* __restrict__ srtN,
    const float* __restrict__ WlE, const float* __restrict__ blE, const float* __restrict__ WrE,
    const float* __restrict__ WlN, const float* __restrict__ blN, const float* __restrict__ WrN,
    float* __restrict__ outE, float* __restrict__ outN, int gbE) {
    if ((int)blockIdx.x < gbE) {
        // edge-side: gather nodes -> hyperedges
        sage_body(xnIn, xeIn, offE, cntE, srtE, WlE, blE, WrE, outE, N_HEDGES,
                  blockIdx.x * 64);
    } else {
        // node-side: gather hyperedges -> nodes
        sage_body(xeIn, xnIn, offN, cntN, srtN, WlN, blN, WrN, outN, N_NODES,
                  (blockIdx.x - gbE) * 64);
    }
}

// ---------------- pooling ----------------
__global__ void pool_kernel(const float* __restrict__ x,
                            const int* __restrict__ batch,
                            float* __restrict__ pool, int rows) {
    __shared__ float sp[NG * HD];  // 16 KB
    for (int t = threadIdx.x; t < NG * HD; t += blockDim.x) sp[t] = 0.f;
    __syncthreads();
    long total = (long)rows * HD;
    long stride = (long)gridDim.x * blockDim.x;
    for (long i = (long)blockIdx.x * blockDim.x + threadIdx.x; i < total; i += stride) {
        int r = (int)(i >> 6), h = (int)(i & 63);
        atomicAdd(&sp[batch[r] * HD + h], x[i]);
    }
    __syncthreads();
    for (int t = threadIdx.x; t < NG * HD; t += blockDim.x)
        if (sp[t] != 0.f) atomicAdd(&pool[t], sp[t]);
}

// batch counts via binary search (sorted batch arrays)
__global__ void batch_counts_bs(const int* __restrict__ node_batch,
                                const int* __restrict__ edge_batch,
                                float* __restrict__ cntBN, float* __restrict__ cntBE) {
    int t = threadIdx.x;
    if (t >= 128) return;
    const int* arr = (t < 64) ? node_batch : edge_batch;
    int n = (t < 64) ? N_NODES : N_HEDGES;
    int g = t & 63;
    int lo1 = 0, hi1 = n;
    while (lo1 < hi1) { int mid = (lo1 + hi1) >> 1; if (arr[mid] < g) lo1 = mid + 1; else hi1 = mid; }
    int lo2 = 0, hi2 = n;
    while (lo2 < hi2) { int mid = (lo2 + hi2) >> 1; if (arr[mid] < g + 1) lo2 = mid + 1; else hi2 = mid; }
    float c = (float)(lo2 - lo1);
    if (t < 64) cntBN[g] = c; else cntBE[g] = c;
}

__global__ void final_kernel(const float* __restrict__ poolN,
                             const float* __restrict__ poolE,
                             const float* __restrict__ cntBN,
                             const float* __restrict__ cntBE,
                             const float* __restrict__ Wout,
                             const float* __restrict__ bout,
                             float* __restrict__ out) {
    int i = blockIdx.x * blockDim.x + threadIdx.x;
    if (i >= NG * 32) return;
    int g = i >> 5, o = i & 31;
    float invN = 1.f / fmaxf(cntBN[g], 1.f);
    float invE = 1.f / fmaxf(cntBE[g], 1.f);
    float s = bout[o];
#pragma unroll 8
    for (int k = 0; k < HD; k++) s += poolN[g * HD + k] * invN * Wout[k * 32 + o];
#pragma unroll 8
    for (int k = 0; k < HD; k++) s += poolE[g * HD + k] * invE * Wout[(HD + k) * 32 + o];
    out[i] = s;
}

extern "C" void kernel_launch(void* const* d_in, const int* in_sizes, int n_in,
                              void* d_out, int out_size, void* d_ws, size_t ws_size,
                              hipStream_t stream) {
    const float* node_x = (const float*)d_in[0];
    const float* edge_x = (const float*)d_in[1];
    const int* n2e_src = (const int*)d_in[2];
    const int* n2e_dst = (const int*)d_in[3];
    const int* e2n_src = (const int*)d_in[4];
    const int* e2n_dst = (const int*)d_in[5];
    const int* node_batch = (const int*)d_in[6];
    const int* edge_batch = (const int*)d_in[7];
    const float* Wn = (const float*)d_in[8];
    const float* bn = (const float*)d_in[9];
    const float* We = (const float*)d_in[10];
    const float* be = (const float*)d_in[11];
    const float* W1l_n2e = (const float*)d_in[12];
    const float* b1l_n2e = (const float*)d_in[13];
    const float* W1r_n2e = (const float*)d_in[14];
    const float* W1l_e2n = (const float*)d_in[15];
    const float* b1l_e2n = (const float*)d_in[16];
    const float* W1r_e2n = (const float*)d_in[17];
    const float* W2l_n2e = (const float*)d_in[18];
    const float* b2l_n2e = (const float*)d_in[19];
    const float* W2r_n2e = (const float*)d_in[20];
    const float* W2l_e2n = (const float*)d_in[21];
    const float* b2l_e2n = (const float*)d_in[22];
    const float* W2r_e2n = (const float*)d_in[23];
    const float* Wout = (const float*)d_in[24];
    const float* bout = (const float*)d_in[25];
    float* out = (float*)d_out;

    // ---- workspace layout ----
    float* ws = (float*)d_ws;
    float* xn = ws;                      // 6.4M floats (also xn2)
    float* xe = xn + N_NODES * HD;       // 1.6M (also xe2)
    float* xe1 = xe + N_HEDGES * HD;     // 1.6M
    float* xn1 = xe1 + N_HEDGES * HD;    // 6.4M
    float* poolN = xn1 + N_NODES * HD;   // 4096
    float* poolE = poolN + NG * HD;      // 4096
    float* cntBN = poolE + NG * HD;      // 64
    float* cntBE = cntBN + NG;           // 64
    int* iws = (int*)(cntBE + NG);
    int* cntE = iws;                     // 25000
    int* cntN = cntE + N_HEDGES;         // 100000
    int* curE = cntN + N_NODES;          // 25000
    int* curN = curE + N_HEDGES;         // 100000
    int* offE = curN + N_NODES;          // 25000
    int* offN = offE + N_HEDGES;         // 100000
    int* srtE = offN + N_NODES;          // 1M
    int* srtN = srtE + N_EDGES;          // 1M
    int* bsumsE = srtN + N_EDGES;        // 32
    int* bsumsN = bsumsE + 32;           // 128

    const int B = 256;

    // ---- CSR build ----
    zero_i32<<<256, B, 0, stream>>>(cntE, 2 * (N_HEDGES + N_NODES));  // cntE..curN contiguous
    count_int<<<(N_EDGES + B - 1) / B, B, 0, stream>>>(n2e_dst, e2n_dst, cntE, cntN);
    {
        int nbE = (N_HEDGES + SCAN_TILE - 1) / SCAN_TILE;  // 25
        int nbN = (N_NODES + SCAN_TILE - 1) / SCAN_TILE;   // 98
        scan_part<<<nbE, SCAN_B, 0, stream>>>(cntE, offE, bsumsE, N_HEDGES);
        scan_part<<<nbN, SCAN_B, 0, stream>>>(cntN, offN, bsumsN, N_NODES);
        scan_top<<<1, 128, 0, stream>>>(bsumsE, nbE);
        scan_top<<<1, 128, 0, stream>>>(bsumsN, nbN);
        scan_add<<<(N_HEDGES + B - 1) / B, B, 0, stream>>>(offE, bsumsE, N_HEDGES);
        scan_add<<<(N_NODES + B - 1) / B, B, 0, stream>>>(offN, bsumsN, N_NODES);
    }
    fill_csr<<<(N_EDGES + B - 1) / B, B, 0, stream>>>(n2e_src, n2e_dst, e2n_src, e2n_dst,
                                                      offE, offN, curE, curN, srtE, srtN);

    // ---- encoders ----
    encode_nodes<<<(N_NODES * HD + B - 1) / B, B, 0, stream>>>(node_x, Wn, bn, xn);
    encode_edges<<<(N_HEDGES * HD + B - 1) / B, B, 0, stream>>>(edge_x, We, be, xe);

    int gbE = (N_HEDGES + 63) / 64;  // 391
    int gbN = (N_NODES + 63) / 64;   // 1563
    int grid = gbE + gbN;            // 1954

    // ---- layer 1 (both directions fused) ----
    sage_layer<<<grid, B, 0, stream>>>(xn, xe, offE, cntE, srtE, offN, cntN, srtN,
                                       W1l_n2e, b1l_n2e, W1r_n2e,
                                       W1l_e2n, b1l_e2n, W1r_e2n,
                                       xe1, xn1, gbE);

    // ---- layer 2 (both directions fused) ----
    sage_layer<<<grid, B, 0, stream>>>(xn1, xe1, offE, cntE, srtE, offN, cntN, srtN,
                                       W2l_n2e, b2l_n2e, W2r_n2e,
                                       W2l_e2n, b2l_e2n, W2r_e2n,
                                       xe /*xe2*/, xn /*xn2*/, gbE);

    // ---- pooling ----
    zero_f32<<<64, B, 0, stream>>>(poolN, 2 * NG * HD);  // poolN+poolE contiguous
    pool_kernel<<<512, B, 0, stream>>>(xn /*xn2*/, node_batch, poolN, N_NODES);
    pool_kernel<<<256, B, 0, stream>>>(xe /*xe2*/, edge_batch, poolE, N_HEDGES);
    batch_counts_bs<<<1, 128, 0, stream>>>(node_batch, edge_batch, cntBN, cntBE);

    // ---- readout ----
    final_kernel<<<(NG * 32 + B - 1) / B, B, 0, stream>>>(poolN, poolE, cntBN, cntBE, Wout, bout, out);
}

// Round 5
// 495.621 us; speedup vs baseline: 4.0797x; 1.3250x over previous
//
#include <hip/hip_runtime.h>

#define N_NODES 100000
#define N_HEDGES 25000
#define N_EDGES 1000000
#define NG 64
#define HD 64

typedef __attribute__((ext_vector_type(4))) float f4;

// ---------------- zero (one contiguous word region: pools + cnt) ----------------
__global__ void zero_words(int* p, int n) {
    int i = blockIdx.x * blockDim.x + threadIdx.x;
    if (i < n) p[i] = 0;
}

// ---------------- CSR build ----------------
// cnt = [cntE(25000) | cntN(100000)], off likewise
__global__ void count_int(const int* __restrict__ n2e_dst,
                          const int* __restrict__ e2n_dst,
                          int* __restrict__ cnt) {
    int i = blockIdx.x * blockDim.x + threadIdx.x;
    if (i < N_EDGES) {
        atomicAdd(&cnt[n2e_dst[i]], 1);
        atomicAdd(&cnt[N_HEDGES + e2n_dst[i]], 1);
    }
}

#define SCAN_B 256
#define SCAN_E 4
#define SCAN_TILE 1024
#define NB_E 25   // ceil(25000/1024)
#define NB_N 98   // ceil(100000/1024)

__global__ void scan_part2(const int* __restrict__ cnt, int* __restrict__ off,
                           int* __restrict__ bsumsE, int* __restrict__ bsumsN) {
    __shared__ int lds[SCAN_B];
    int b = blockIdx.x;
    const int* in; int* out; int* bs; int n; int lb;
    if (b < NB_E) { in = cnt; out = off; bs = bsumsE; n = N_HEDGES; lb = b; }
    else { in = cnt + N_HEDGES; out = off + N_HEDGES; bs = bsumsN; n = N_NODES; lb = b - NB_E; }
    int base = lb * SCAN_TILE;
    int t = threadIdx.x;
    int v[SCAN_E];
    int s = 0;
#pragma unroll
    for (int e = 0; e < SCAN_E; e++) {
        int idx = base + t * SCAN_E + e;
        v[e] = (idx < n) ? in[idx] : 0;
        s += v[e];
    }
    lds[t] = s;
    __syncthreads();
    for (int off2 = 1; off2 < SCAN_B; off2 <<= 1) {
        int x = (t >= off2) ? lds[t - off2] : 0;
        __syncthreads();
        lds[t] += x;
        __syncthreads();
    }
    int excl = (t > 0) ? lds[t - 1] : 0;
    if (t == SCAN_B - 1) bs[lb] = lds[t];
    int run = excl;
#pragma unroll
    for (int e = 0; e < SCAN_E; e++) {
        int idx = base + t * SCAN_E + e;
        if (idx < n) out[idx] = run;
        run += v[e];
    }
}
__global__ void scan_top2(int* bsumsE, int* bsumsN) {
    __shared__ int s[128];
    int* bs = (blockIdx.x == 0) ? bsumsE : bsumsN;
    int nb = (blockIdx.x == 0) ? NB_E : NB_N;
    int t = threadIdx.x;
    int v = (t < nb) ? bs[t] : 0;
    s[t] = v;
    __syncthreads();
    for (int off = 1; off < 128; off <<= 1) {
        int x = (t >= off) ? s[t - off] : 0;
        __syncthreads();
        s[t] += x;
        __syncthreads();
    }
    if (t < nb) bs[t] = s[t] - v;  // exclusive
}
__global__ void scan_add2(int* __restrict__ off, const int* __restrict__ bsumsE,
                          const int* __restrict__ bsumsN) {
    int i = blockIdx.x * blockDim.x + threadIdx.x;
    if (i < N_HEDGES) off[i] += bsumsE[i >> 10];
    else if (i < N_HEDGES + N_NODES) off[i] += bsumsN[(i - N_HEDGES) >> 10];
}

// fill via atomicSub on cnt (positions deg-1..0); cnt ends at zero (unused after)
__global__ void fill_csr(const int* __restrict__ n2e_src, const int* __restrict__ n2e_dst,
                         const int* __restrict__ e2n_src, const int* __restrict__ e2n_dst,
                         const int* __restrict__ off, int* __restrict__ cnt,
                         int* __restrict__ srtE, int* __restrict__ srtN) {
    int i = blockIdx.x * blockDim.x + threadIdx.x;
    if (i < N_EDGES) {
        int d = n2e_dst[i];
        int p = atomicSub(&cnt[d], 1) - 1;
        srtE[off[d] + p] = n2e_src[i];
        int d2 = N_HEDGES + e2n_dst[i];
        int p2 = atomicSub(&cnt[d2], 1) - 1;
        srtN[off[d2] + p2] = e2n_src[i];
    }
}

// ---------------- fused encoder ----------------
__global__ void encode_fused(const float* __restrict__ node_x, const float* __restrict__ edge_x,
                             const float* __restrict__ Wn, const float* __restrict__ bn,
                             const float* __restrict__ We, const float* __restrict__ be,
                             float* __restrict__ xn, float* __restrict__ xe) {
    int i = blockIdx.x * blockDim.x + threadIdx.x;
    if (i < N_NODES * HD) {
        int node = i >> 6, h = i & 63;
        float v = node_x[node] * Wn[h] + bn[h];
        xn[i] = v > 0.f ? v : 0.f;
    } else if (i < (N_NODES + N_HEDGES) * HD) {
        int j = i - N_NODES * HD;
        int e = j >> 6, h = j & 63;
        float v = edge_x[2 * e] * We[h] + edge_x[2 * e + 1] * We[HD + h] + be[h];
        xe[j] = v > 0.f ? v : 0.f;
    }
}

// ---------------- gather-mean (both directions, no LDS, wave per row) ----------------
__global__ __launch_bounds__(256) void gather_layer(
    const float* __restrict__ xnFeat, const float* __restrict__ xeFeat,
    const int* __restrict__ off, const int* __restrict__ srtE, const int* __restrict__ srtN,
    float* __restrict__ aggE, float* __restrict__ aggN) {
    int lane = threadIdx.x & 63;
    int w = blockIdx.x * 4 + (threadIdx.x >> 6);
    int NW = gridDim.x * 4;
    int esub = lane >> 4;  // 0..3 edge sublane
    int fq = lane & 15;    // f4 chunk
    const int RT = N_HEDGES + N_NODES;
    for (int r = w; r < RT; r += NW) {
        const float* xsrc; const int* srt; float* agg; int rr; int lo, hi;
        if (r < N_HEDGES) {
            rr = r;
            lo = off[rr];
            hi = (rr + 1 < N_HEDGES) ? off[rr + 1] : N_EDGES;
            xsrc = xnFeat; srt = srtE; agg = aggE;
        } else {
            rr = r - N_HEDGES;
            lo = off[N_HEDGES + rr];
            hi = (rr + 1 < N_NODES) ? off[N_HEDGES + rr + 1] : N_EDGES;
            xsrc = xeFeat; srt = srtN; agg = aggN;
        }
        int deg = hi - lo;
        f4 acc0 = {0.f, 0.f, 0.f, 0.f}, acc1 = {0.f, 0.f, 0.f, 0.f};
        for (int j0 = 0; j0 < deg; j0 += 64) {
            int chunk = deg - j0;
            if (chunk > 64) chunk = 64;
            int idv = (j0 + lane < deg) ? srt[lo + j0 + lane] : 0;
            int jj = 0;
            for (; jj + 8 <= chunk; jj += 8) {
                int s0 = __shfl(idv, jj + esub);
                int s1 = __shfl(idv, jj + 4 + esub);
                f4 v0 = *(const f4*)(xsrc + (long)s0 * HD + fq * 4);
                f4 v1 = *(const f4*)(xsrc + (long)s1 * HD + fq * 4);
                acc0 += v0;
                acc1 += v1;
            }
            for (; jj < chunk; jj += 4) {
                int e = jj + esub;
                int s = __shfl(idv, e);
                f4 v = *(const f4*)(xsrc + (long)s * HD + fq * 4);
                if (e < chunk) acc0 += v;
            }
        }
        f4 acc = acc0 + acc1;
#pragma unroll
        for (int c = 0; c < 4; c++) {
            acc[c] += __shfl_xor(acc[c], 16);
            acc[c] += __shfl_xor(acc[c], 32);
        }
        if (lane < 16) {
            float invd = 1.f / (float)(deg > 1 ? deg : 1);
            *(f4*)(agg + (long)rr * HD + fq * 4) = acc * invd;
        }
    }
}

// ---------------- combine: out = relu(agg@Wl + bl + xdst@Wr), in-place over agg ----------------
__device__ __forceinline__ void combine_body(
    const float* agg, const float* __restrict__ xdst,
    const float* __restrict__ Wl, const float* __restrict__ bl, const float* __restrict__ Wr,
    float* out, int rows, int row0) {
    __shared__ float sW0[32 * 64];
    __shared__ float sW1[32 * 64];
    __shared__ float sA[64][68];
    __shared__ float sX[64][68];

    int t = threadIdx.x;
    // stage agg + xdst tiles (coalesced f4)
    {
        int r = t >> 2, c0s = (t & 3) * 16;
        int gr = row0 + r;
        if (gr < rows) {
            const f4* ga = (const f4*)(agg + (long)gr * HD + c0s);
            const f4* gx = (const f4*)(xdst + (long)gr * HD + c0s);
            f4* la = (f4*)&sA[r][c0s];
            f4* lx = (f4*)&sX[r][c0s];
#pragma unroll
            for (int q = 0; q < 4; q++) { la[q] = ga[q]; lx[q] = gx[q]; }
        }
    }

    int tc = t & 15, tr = t >> 4;
    int c0 = tc * 4, m0 = tr * 4;
    f4 acc[4];
    f4 blv = *(const f4*)(bl + c0);
#pragma unroll
    for (int i = 0; i < 4; i++) acc[i] = blv;

    for (int half = 0; half < 2; half++) {
        __syncthreads();
        for (int i = t; i < 32 * 64; i += 256) {
            sW0[i] = Wl[half * 2048 + i];
            sW1[i] = Wr[half * 2048 + i];
        }
        __syncthreads();
#pragma unroll
        for (int kq = 0; kq < 8; kq++) {
            int k0 = kq * 4;
            int ka = half * 32 + k0;
            f4 wl[4], wr[4];
#pragma unroll
            for (int kk = 0; kk < 4; kk++) {
                wl[kk] = *(const f4*)&sW0[(k0 + kk) * 64 + c0];
                wr[kk] = *(const f4*)&sW1[(k0 + kk) * 64 + c0];
            }
#pragma unroll
            for (int i = 0; i < 4; i++) {
                f4 a = *(const f4*)&sA[m0 + i][ka];
                f4 x = *(const f4*)&sX[m0 + i][ka];
#pragma unroll
                for (int kk = 0; kk < 4; kk++)
                    acc[i] += a[kk] * wl[kk] + x[kk] * wr[kk];
            }
        }
    }

#pragma unroll
    for (int i = 0; i < 4; i++) {
        int gr = row0 + m0 + i;
        if (gr < rows) {
            f4 v = acc[i];
#pragma unroll
            for (int j = 0; j < 4; j++) v[j] = fmaxf(v[j], 0.f);
            *(f4*)(out + (long)gr * HD + c0) = v;
        }
    }
}

__global__ __launch_bounds__(256) void combine_layer(
    const float* aggE, const float* __restrict__ xeDst,
    const float* aggN, const float* __restrict__ xnDst,
    const float* __restrict__ WlE, const float* __restrict__ blE, const float* __restrict__ WrE,
    const float* __restrict__ WlN, const float* __restrict__ blN, const float* __restrict__ WrN,
    float* outE, float* outN, int gbE) {
    if ((int)blockIdx.x < gbE)
        combine_body(aggE, xeDst, WlE, blE, WrE, outE, N_HEDGES, blockIdx.x * 64);
    else
        combine_body(aggN, xnDst, WlN, blN, WrN, outN, N_NODES, (blockIdx.x - gbE) * 64);
}

// ---------------- pooling via sorted batch ranges (no global-atomic storm) ----------------
__device__ __forceinline__ int lower_bound_dev(const int* arr, int n, int key) {
    int lo = 0, hi = n;
    while (lo < hi) { int mid = (lo + hi) >> 1; if (arr[mid] < key) lo = mid + 1; else hi = mid; }
    return lo;
}

#define PB_N 4  // blocks per graph (nodes)
#define PB_E 2  // blocks per graph (edges)
__global__ __launch_bounds__(256) void pool_sorted(
    const float* __restrict__ xn2, const float* __restrict__ xe2,
    const int* __restrict__ node_batch, const int* __restrict__ edge_batch,
    float* __restrict__ poolN, float* __restrict__ poolE) {
    __shared__ float sp[4][64];
    int b = blockIdx.x;
    const float* x; const int* batch; float* pool; int n, g, part, P;
    if (b < NG * PB_N) { x = xn2; batch = node_batch; pool = poolN; n = N_NODES; g = b / PB_N; part = b % PB_N; P = PB_N; }
    else { b -= NG * PB_N; x = xe2; batch = edge_batch; pool = poolE; n = N_HEDGES; g = b / PB_E; part = b % PB_E; P = PB_E; }
    int s = lower_bound_dev(batch, n, g);
    int e = lower_bound_dev(batch, n, g + 1);
    int len = e - s;
    int start = s + (int)(((long)len * part) / P);
    int end = s + (int)(((long)len * (part + 1)) / P);
    int lane = threadIdx.x & 63, wv = threadIdx.x >> 6;
    float acc = 0.f;
    for (int r = start + wv; r < end; r += 4) acc += x[(long)r * HD + lane];
    sp[wv][lane] = acc;
    __syncthreads();
    if (threadIdx.x < 64) {
        float v = sp[0][lane] + sp[1][lane] + sp[2][lane] + sp[3][lane];
        if (v != 0.f) atomicAdd(&pool[g * HD + lane], v);
    }
}

__global__ void batch_counts_bs(const int* __restrict__ node_batch,
                                const int* __restrict__ edge_batch,
                                float* __restrict__ cntBN, float* __restrict__ cntBE) {
    int t = threadIdx.x;
    if (t >= 128) return;
    const int* arr = (t < 64) ? node_batch : edge_batch;
    int n = (t < 64) ? N_NODES : N_HEDGES;
    int g = t & 63;
    int lo = lower_bound_dev(arr, n, g);
    int hi = lower_bound_dev(arr, n, g + 1);
    float c = (float)(hi - lo);
    if (t < 64) cntBN[g] = c; else cntBE[g] = c;
}

__global__ void final_kernel(const float* __restrict__ poolN,
                             const float* __restrict__ poolE,
                             const float* __restrict__ cntBN,
                             const float* __restrict__ cntBE,
                             const float* __restrict__ Wout,
                             const float* __restrict__ bout,
                             float* __restrict__ out) {
    int i = blockIdx.x * blockDim.x + threadIdx.x;
    if (i >= NG * 32) return;
    int g = i >> 5, o = i & 31;
    float invN = 1.f / fmaxf(cntBN[g], 1.f);
    float invE = 1.f / fmaxf(cntBE[g], 1.f);
    float s = bout[o];
#pragma unroll 8
    for (int k = 0; k < HD; k++) s += poolN[g * HD + k] * invN * Wout[k * 32 + o];
#pragma unroll 8
    for (int k = 0; k < HD; k++) s += poolE[g * HD + k] * invE * Wout[(HD + k) * 32 + o];
    out[i] = s;
}

extern "C" void kernel_launch(void* const* d_in, const int* in_sizes, int n_in,
                              void* d_out, int out_size, void* d_ws, size_t ws_size,
                              hipStream_t stream) {
    const float* node_x = (const float*)d_in[0];
    const float* edge_x = (const float*)d_in[1];
    const int* n2e_src = (const int*)d_in[2];
    const int* n2e_dst = (const int*)d_in[3];
    const int* e2n_src = (const int*)d_in[4];
    const int* e2n_dst = (const int*)d_in[5];
    const int* node_batch = (const int*)d_in[6];
    const int* edge_batch = (const int*)d_in[7];
    const float* Wn = (const float*)d_in[8];
    const float* bn = (const float*)d_in[9];
    const float* We = (const float*)d_in[10];
    const float* be = (const float*)d_in[11];
    const float* W1l_n2e = (const float*)d_in[12];
    const float* b1l_n2e = (const float*)d_in[13];
    const float* W1r_n2e = (const float*)d_in[14];
    const float* W1l_e2n = (const float*)d_in[15];
    const float* b1l_e2n = (const float*)d_in[16];
    const float* W1r_e2n = (const float*)d_in[17];
    const float* W2l_n2e = (const float*)d_in[18];
    const float* b2l_n2e = (const float*)d_in[19];
    const float* W2r_n2e = (const float*)d_in[20];
    const float* W2l_e2n = (const float*)d_in[21];
    const float* b2l_e2n = (const float*)d_in[22];
    const float* W2r_e2n = (const float*)d_in[23];
    const float* Wout = (const float*)d_in[24];
    const float* bout = (const float*)d_in[25];
    float* out = (float*)d_out;

    // ---- workspace layout (buffer reuse; total ~73 MB) ----
    // A(6.4M): xn -> aggN2 -> xn2 (in-place)
    // F(6.4M): aggN1 -> xn1 (in-place)
    // B(1.6M): xe -> aggE2 -> xe2 (in-place)
    // E(1.6M): aggE1 -> xe1 (in-place)
    float* W = (float*)d_ws;
    float* A = W;
    float* F = A + N_NODES * HD;
    float* B_ = F + N_NODES * HD;
    float* E_ = B_ + N_HEDGES * HD;
    float* poolN = E_ + N_HEDGES * HD;  // 4096
    float* poolE = poolN + NG * HD;     // 4096
    float* cntBN = poolE + NG * HD;     // 64
    float* cntBE = cntBN + NG;          // 64
    int* cnt = (int*)(cntBE + NG);      // 125000 (cntE | cntN) - adjacent to pools for one zero pass? see below
    int* off = cnt + (N_HEDGES + N_NODES);   // 125000
    int* srtE = off + (N_HEDGES + N_NODES);  // 1M
    int* srtN = srtE + N_EDGES;              // 1M
    int* bsumsE = srtN + N_EDGES;            // 32
    int* bsumsN = bsumsE + 32;               // 128

    const int Bt = 256;

    // ---- zero: pools (8192 f) + cntB (128) + cnt (125000 i) are contiguous words ----
    int zeroN = 2 * NG * HD + 2 * NG + (N_HEDGES + N_NODES);
    zero_words<<<(zeroN + Bt - 1) / Bt, Bt, 0, stream>>>((int*)poolN, zeroN);

    // ---- CSR build ----
    count_int<<<(N_EDGES + Bt - 1) / Bt, Bt, 0, stream>>>(n2e_dst, e2n_dst, cnt);
    scan_part2<<<NB_E + NB_N, SCAN_B, 0, stream>>>(cnt, off, bsumsE, bsumsN);
    scan_top2<<<2, 128, 0, stream>>>(bsumsE, bsumsN);
    scan_add2<<<(N_HEDGES + N_NODES + Bt - 1) / Bt, Bt, 0, stream>>>(off, bsumsE, bsumsN);
    fill_csr<<<(N_EDGES + Bt - 1) / Bt, Bt, 0, stream>>>(n2e_src, n2e_dst, e2n_src, e2n_dst,
                                                         off, cnt, srtE, srtN);

    // ---- encoders (xn -> A, xe -> B_) ----
    encode_fused<<<((N_NODES + N_HEDGES) * HD + Bt - 1) / Bt, Bt, 0, stream>>>(
        node_x, edge_x, Wn, bn, We, be, A, B_);

    int gbE = (N_HEDGES + 63) / 64;  // 391
    int gbN = (N_NODES + 63) / 64;   // 1563
    int gridC = gbE + gbN;           // 1954
    int gridG = 2048;

    // ---- layer 1: gather (xn=A, xe=B_) -> aggE1=E_, aggN1=F; combine in place ----
    gather_layer<<<gridG, Bt, 0, stream>>>(A, B_, off, srtE, srtN, E_, F);
    combine_layer<<<gridC, Bt, 0, stream>>>(E_, B_, F, A,
                                            W1l_n2e, b1l_n2e, W1r_n2e,
                                            W1l_e2n, b1l_e2n, W1r_e2n,
                                            E_ /*xe1*/, F /*xn1*/, gbE);

    // ---- layer 2: gather (xn1=F, xe1=E_) -> aggE2=B_, aggN2=A; combine in place ----
    gather_layer<<<gridG, Bt, 0, stream>>>(F, E_, off, srtE, srtN, B_, A);
    combine_layer<<<gridC, Bt, 0, stream>>>(B_, E_, A, F,
                                            W2l_n2e, b2l_n2e, W2r_n2e,
                                            W2l_e2n, b2l_e2n, W2r_e2n,
                                            B_ /*xe2*/, A /*xn2*/, gbE);

    // ---- pooling (sorted ranges) + counts + readout ----
    pool_sorted<<<NG * PB_N + NG * PB_E, Bt, 0, stream>>>(A, B_, node_batch, edge_batch, poolN, poolE);
    batch_counts_bs<<<1, 128, 0, stream>>>(node_batch, edge_batch, cntBN, cntBE);
    final_kernel<<<(NG * 32 + Bt - 1) / Bt, Bt, 0, stream>>>(poolN, poolE, cntBN, cntBE, Wout, bout, out);
}

// Round 6
// 319.256 us; speedup vs baseline: 6.3334x; 1.5524x over previous
//
#include <hip/hip_runtime.h>

#define N_NODES 100000
#define N_HEDGES 25000
#define N_EDGES 1000000
#define NG 64
#define HD 64

// binned CSR build params
#define EB_SH 8
#define EB_NB 98      // ceil(25000/256)
#define EB_CAP 12000  // mean 10240, sigma~101 -> +17 sigma
#define NB_SH 9
#define NB_NB 196     // ceil(100000/512)
#define NB_CAP 6200   // mean 5120, sigma~71 -> +15 sigma
#define TILE 4096
#define TPS 245       // tiles per side = ceil(1e6/4096)

typedef __attribute__((ext_vector_type(4))) float f4;

// ---------------- zero (pools + batch counts + bucket cursors) ----------------
__global__ void zero_words(int* p, int n) {
    int i = blockIdx.x * blockDim.x + threadIdx.x;
    if (i < n) p[i] = 0;
}

// ---------------- pass 1: LDS-binned scatter of packed (dst_local, src) pairs ----------------
__global__ __launch_bounds__(256) void bin_pass(
    const int* __restrict__ n2e_src, const int* __restrict__ n2e_dst,
    const int* __restrict__ e2n_src, const int* __restrict__ e2n_dst,
    int* __restrict__ binE, int* __restrict__ binN,
    int* __restrict__ gcntE, int* __restrict__ gcntN) {
    __shared__ int pairsL[TILE];
    __shared__ int hist[256], scanv[256], start[256], curs[256], gbase[256];
    int t = threadIdx.x;
    int side = (int)blockIdx.x >= TPS;
    int lb = blockIdx.x - (side ? TPS : 0);
    const int* dsts = side ? e2n_dst : n2e_dst;
    const int* srcs = side ? e2n_src : n2e_src;
    int NB = side ? NB_NB : EB_NB;
    int SH = side ? NB_SH : EB_SH;
    int CAP = side ? NB_CAP : EB_CAP;
    int* bins = side ? binN : binE;
    int* gcnt = side ? gcntN : gcntE;
    int base = lb * TILE;

    hist[t] = 0;
    __syncthreads();

    int pair[16], buck[16];
#pragma unroll
    for (int k = 0; k < 16; k++) {
        int e = base + k * 256 + t;
        if (e < N_EDGES) {
            int d = dsts[e];
            int s = srcs[e];
            buck[k] = d >> SH;
            pair[k] = ((d & ((1 << SH) - 1)) << 17) | s;
            atomicAdd(&hist[buck[k]], 1);
        } else buck[k] = -1;
    }
    __syncthreads();
    int v = hist[t];
    scanv[t] = v;
    __syncthreads();
    for (int o = 1; o < 256; o <<= 1) {
        int x = (t >= o) ? scanv[t - o] : 0;
        __syncthreads();
        scanv[t] += x;
        __syncthreads();
    }
    start[t] = scanv[t] - v;
    curs[t] = scanv[t] - v;
    if (t < NB && v > 0) gbase[t] = t * CAP + atomicAdd(&gcnt[t], v);
    __syncthreads();
    int total = scanv[255];
#pragma unroll
    for (int k = 0; k < 16; k++) {
        if (buck[k] >= 0) {
            int slot = atomicAdd(&curs[buck[k]], 1);
            pairsL[slot] = pair[k];
        }
    }
    __syncthreads();
    // copy grouped runs to global bucket segments (coalesced-ish)
    for (int i = t; i < total; i += 256) {
        int lo = 0, hi = NB - 1;  // max b with start[b] <= i
        while (lo < hi) { int mid = (lo + hi + 1) >> 1; if (start[mid] <= i) lo = mid; else hi = mid - 1; }
        bins[gbase[lo] + (i - start[lo])] = pairsL[i];
    }
}

// ---------------- pass 2: per-bucket fine CSR fill (one block owns one bucket) ----------------
__global__ __launch_bounds__(512) void fine_fill(
    const int* __restrict__ binE, const int* __restrict__ binN,
    const int* __restrict__ gcntE, const int* __restrict__ gcntN,
    int* __restrict__ off, int* __restrict__ deg,
    int* __restrict__ srtE, int* __restrict__ srtN) {
    __shared__ int hist[512], scanv[512];
    int t = threadIdx.x;
    int side = (int)blockIdx.x >= EB_NB;
    int b = blockIdx.x - (side ? EB_NB : 0);
    int NROWS = side ? 512 : 256;
    int CAP = side ? NB_CAP : EB_CAP;
    const int* bins = (side ? binN : binE) + (long)b * CAP;
    int* srt = (side ? srtN : srtE) + (long)b * CAP;
    int cnt_b = (side ? gcntN : gcntE)[b];
    int rowbase = side ? (N_HEDGES + b * 512) : b * 256;
    int nrows = (side ? N_NODES : N_HEDGES) - (side ? b * 512 : b * 256);
    if (nrows > NROWS) nrows = NROWS;

    hist[t] = 0;
    __syncthreads();
    for (int i = t; i < cnt_b; i += 512) atomicAdd(&hist[bins[i] >> 17], 1);
    __syncthreads();
    int v = hist[t];
    scanv[t] = v;
    __syncthreads();
    for (int o = 1; o < 512; o <<= 1) {
        int x = (t >= o) ? scanv[t - o] : 0;
        __syncthreads();
        scanv[t] += x;
        __syncthreads();
    }
    int excl = scanv[t] - v;
    if (t < nrows) { off[rowbase + t] = b * CAP + excl; deg[rowbase + t] = v; }
    scanv[t] = excl;  // becomes the per-row cursor
    __syncthreads();
    for (int i = t; i < cnt_b; i += 512) {
        int p = bins[i];
        int pos = atomicAdd(&scanv[p >> 17], 1);
        srt[pos] = p & 0x1FFFF;
    }
}

// ---------------- fused encoder ----------------
__global__ void encode_fused(const float* __restrict__ node_x, const float* __restrict__ edge_x,
                             const float* __restrict__ Wn, const float* __restrict__ bn,
                             const float* __restrict__ We, const float* __restrict__ be,
                             float* __restrict__ xn, float* __restrict__ xe) {
    int i = blockIdx.x * blockDim.x + threadIdx.x;
    if (i < N_NODES * HD) {
        int node = i >> 6, h = i & 63;
        float v = node_x[node] * Wn[h] + bn[h];
        xn[i] = v > 0.f ? v : 0.f;
    } else if (i < (N_NODES + N_HEDGES) * HD) {
        int j = i - N_NODES * HD;
        int e = j >> 6, h = j & 63;
        float v = edge_x[2 * e] * We[h] + edge_x[2 * e + 1] * We[HD + h] + be[h];
        xe[j] = v > 0.f ? v : 0.f;
    }
}

// ---------------- gather-mean (both directions, no LDS, wave per row) ----------------
__global__ __launch_bounds__(256) void gather_layer(
    const float* __restrict__ xnFeat, const float* __restrict__ xeFeat,
    const int* __restrict__ off, const int* __restrict__ deg,
    const int* __restrict__ srtE, const int* __restrict__ srtN,
    float* __restrict__ aggE, float* __restrict__ aggN) {
    int lane = threadIdx.x & 63;
    int w = blockIdx.x * 4 + (threadIdx.x >> 6);
    int NW = gridDim.x * 4;
    int esub = lane >> 4;  // 0..3 edge sublane
    int fq = lane & 15;    // f4 chunk
    const int RT = N_HEDGES + N_NODES;
    for (int r = w; r < RT; r += NW) {
        const float* xsrc; const int* srt; float* agg; int rr, idx;
        if (r < N_HEDGES) {
            rr = r; idx = rr;
            xsrc = xnFeat; srt = srtE; agg = aggE;
        } else {
            rr = r - N_HEDGES; idx = N_HEDGES + rr;
            xsrc = xeFeat; srt = srtN; agg = aggN;
        }
        int lo = off[idx];
        int dg = deg[idx];
        f4 acc0 = {0.f, 0.f, 0.f, 0.f}, acc1 = {0.f, 0.f, 0.f, 0.f};
        for (int j0 = 0; j0 < dg; j0 += 64) {
            int chunk = dg - j0;
            if (chunk > 64) chunk = 64;
            int idv = (j0 + lane < dg) ? srt[lo + j0 + lane] : 0;
            int jj = 0;
            for (; jj + 8 <= chunk; jj += 8) {
                int s0 = __shfl(idv, jj + esub);
                int s1 = __shfl(idv, jj + 4 + esub);
                f4 v0 = *(const f4*)(xsrc + (long)s0 * HD + fq * 4);
                f4 v1 = *(const f4*)(xsrc + (long)s1 * HD + fq * 4);
                acc0 += v0;
                acc1 += v1;
            }
            for (; jj < chunk; jj += 4) {
                int e = jj + esub;
                int s = __shfl(idv, e);
                f4 vv = *(const f4*)(xsrc + (long)s * HD + fq * 4);
                if (e < chunk) acc0 += vv;
            }
        }
        f4 acc = acc0 + acc1;
#pragma unroll
        for (int c = 0; c < 4; c++) {
            acc[c] += __shfl_xor(acc[c], 16);
            acc[c] += __shfl_xor(acc[c], 32);
        }
        if (lane < 16) {
            float invd = 1.f / (float)(dg > 1 ? dg : 1);
            *(f4*)(agg + (long)rr * HD + fq * 4) = acc * invd;
        }
    }
}

// ---------------- combine: out = relu(agg@Wl + bl + xdst@Wr), in-place over agg ----------------
__device__ __forceinline__ void combine_body(
    const float* agg, const float* __restrict__ xdst,
    const float* __restrict__ Wl, const float* __restrict__ bl, const float* __restrict__ Wr,
    float* out, int rows, int row0) {
    __shared__ float sW0[32 * 64];
    __shared__ float sW1[32 * 64];
    __shared__ float sA[64][68];
    __shared__ float sX[64][68];

    int t = threadIdx.x;
    {
        int r = t >> 2, c0s = (t & 3) * 16;
        int gr = row0 + r;
        if (gr < rows) {
            const f4* ga = (const f4*)(agg + (long)gr * HD + c0s);
            const f4* gx = (const f4*)(xdst + (long)gr * HD + c0s);
            f4* la = (f4*)&sA[r][c0s];
            f4* lx = (f4*)&sX[r][c0s];
#pragma unroll
            for (int q = 0; q < 4; q++) { la[q] = ga[q]; lx[q] = gx[q]; }
        }
    }

    int tc = t & 15, tr = t >> 4;
    int c0 = tc * 4, m0 = tr * 4;
    f4 acc[4];
    f4 blv = *(const f4*)(bl + c0);
#pragma unroll
    for (int i = 0; i < 4; i++) acc[i] = blv;

    for (int half = 0; half < 2; half++) {
        __syncthreads();
        for (int i = t; i < 32 * 64; i += 256) {
            sW0[i] = Wl[half * 2048 + i];
            sW1[i] = Wr[half * 2048 + i];
        }
        __syncthreads();
#pragma unroll
        for (int kq = 0; kq < 8; kq++) {
            int k0 = kq * 4;
            int ka = half * 32 + k0;
            f4 wl[4], wr[4];
#pragma unroll
            for (int kk = 0; kk < 4; kk++) {
                wl[kk] = *(const f4*)&sW0[(k0 + kk) * 64 + c0];
                wr[kk] = *(const f4*)&sW1[(k0 + kk) * 64 + c0];
            }
#pragma unroll
            for (int i = 0; i < 4; i++) {
                f4 a = *(const f4*)&sA[m0 + i][ka];
                f4 x = *(const f4*)&sX[m0 + i][ka];
#pragma unroll
                for (int kk = 0; kk < 4; kk++)
                    acc[i] += a[kk] * wl[kk] + x[kk] * wr[kk];
            }
        }
    }

#pragma unroll
    for (int i = 0; i < 4; i++) {
        int gr = row0 + m0 + i;
        if (gr < rows) {
            f4 v = acc[i];
#pragma unroll
            for (int j = 0; j < 4; j++) v[j] = fmaxf(v[j], 0.f);
            *(f4*)(out + (long)gr * HD + c0) = v;
        }
    }
}

__global__ __launch_bounds__(256) void combine_layer(
    const float* aggE, const float* __restrict__ xeDst,
    const float* aggN, const float* __restrict__ xnDst,
    const float* __restrict__ WlE, const float* __restrict__ blE, const float* __restrict__ WrE,
    const float* __restrict__ WlN, const float* __restrict__ blN, const float* __restrict__ WrN,
    float* outE, float* outN, int gbE) {
    if ((int)blockIdx.x < gbE)
        combine_body(aggE, xeDst, WlE, blE, WrE, outE, N_HEDGES, blockIdx.x * 64);
    else
        combine_body(aggN, xnDst, WlN, blN, WrN, outN, N_NODES, (blockIdx.x - gbE) * 64);
}

// ---------------- pooling via sorted batch ranges ----------------
__device__ __forceinline__ int lower_bound_dev(const int* arr, int n, int key) {
    int lo = 0, hi = n;
    while (lo < hi) { int mid = (lo + hi) >> 1; if (arr[mid] < key) lo = mid + 1; else hi = mid; }
    return lo;
}

#define PB_N 4
#define PB_E 2
__global__ __launch_bounds__(256) void pool_sorted(
    const float* __restrict__ xn2, const float* __restrict__ xe2,
    const int* __restrict__ node_batch, const int* __restrict__ edge_batch,
    float* __restrict__ poolN, float* __restrict__ poolE) {
    __shared__ float sp[4][64];
    int b = blockIdx.x;
    const float* x; const int* batch; float* pool; int n, g, part, P;
    if (b < NG * PB_N) { x = xn2; batch = node_batch; pool = poolN; n = N_NODES; g = b / PB_N; part = b % PB_N; P = PB_N; }
    else { b -= NG * PB_N; x = xe2; batch = edge_batch; pool = poolE; n = N_HEDGES; g = b / PB_E; part = b % PB_E; P = PB_E; }
    int s = lower_bound_dev(batch, n, g);
    int e = lower_bound_dev(batch, n, g + 1);
    int len = e - s;
    int start = s + (int)(((long)len * part) / P);
    int end = s + (int)(((long)len * (part + 1)) / P);
    int lane = threadIdx.x & 63, wv = threadIdx.x >> 6;
    float acc = 0.f;
    for (int r = start + wv; r < end; r += 4) acc += x[(long)r * HD + lane];
    sp[wv][lane] = acc;
    __syncthreads();
    if (threadIdx.x < 64) {
        float v = sp[0][lane] + sp[1][lane] + sp[2][lane] + sp[3][lane];
        if (v != 0.f) atomicAdd(&pool[g * HD + lane], v);
    }
}

__global__ void batch_counts_bs(const int* __restrict__ node_batch,
                                const int* __restrict__ edge_batch,
                                float* __restrict__ cntBN, float* __restrict__ cntBE) {
    int t = threadIdx.x;
    if (t >= 128) return;
    const int* arr = (t < 64) ? node_batch : edge_batch;
    int n = (t < 64) ? N_NODES : N_HEDGES;
    int g = t & 63;
    int lo = lower_bound_dev(arr, n, g);
    int hi = lower_bound_dev(arr, n, g + 1);
    float c = (float)(hi - lo);
    if (t < 64) cntBN[g] = c; else cntBE[g] = c;
}

__global__ void final_kernel(const float* __restrict__ poolN,
                             const float* __restrict__ poolE,
                             const float* __restrict__ cntBN,
                             const float* __restrict__ cntBE,
                             const float* __restrict__ Wout,
                             const float* __restrict__ bout,
                             float* __restrict__ out) {
    int i = blockIdx.x * blockDim.x + threadIdx.x;
    if (i >= NG * 32) return;
    int g = i >> 5, o = i & 31;
    float invN = 1.f / fmaxf(cntBN[g], 1.f);
    float invE = 1.f / fmaxf(cntBE[g], 1.f);
    float s = bout[o];
#pragma unroll 8
    for (int k = 0; k < HD; k++) s += poolN[g * HD + k] * invN * Wout[k * 32 + o];
#pragma unroll 8
    for (int k = 0; k < HD; k++) s += poolE[g * HD + k] * invE * Wout[(HD + k) * 32 + o];
    out[i] = s;
}

extern "C" void kernel_launch(void* const* d_in, const int* in_sizes, int n_in,
                              void* d_out, int out_size, void* d_ws, size_t ws_size,
                              hipStream_t stream) {
    const float* node_x = (const float*)d_in[0];
    const float* edge_x = (const float*)d_in[1];
    const int* n2e_src = (const int*)d_in[2];
    const int* n2e_dst = (const int*)d_in[3];
    const int* e2n_src = (const int*)d_in[4];
    const int* e2n_dst = (const int*)d_in[5];
    const int* node_batch = (const int*)d_in[6];
    const int* edge_batch = (const int*)d_in[7];
    const float* Wn = (const float*)d_in[8];
    const float* bn = (const float*)d_in[9];
    const float* We = (const float*)d_in[10];
    const float* be = (const float*)d_in[11];
    const float* W1l_n2e = (const float*)d_in[12];
    const float* b1l_n2e = (const float*)d_in[13];
    const float* W1r_n2e = (const float*)d_in[14];
    const float* W1l_e2n = (const float*)d_in[15];
    const float* b1l_e2n = (const float*)d_in[16];
    const float* W1r_e2n = (const float*)d_in[17];
    const float* W2l_n2e = (const float*)d_in[18];
    const float* b2l_n2e = (const float*)d_in[19];
    const float* W2r_n2e = (const float*)d_in[20];
    const float* W2l_e2n = (const float*)d_in[21];
    const float* b2l_e2n = (const float*)d_in[22];
    const float* W2r_e2n = (const float*)d_in[23];
    const float* Wout = (const float*)d_in[24];
    const float* bout = (const float*)d_in[25];
    float* out = (float*)d_out;

    // ---- workspace layout (~84 MB) ----
    float* Wp = (float*)d_ws;
    float* A = Wp;                       // 6.4M: xn -> aggN2 -> xn2
    float* F = A + N_NODES * HD;         // 6.4M: aggN1 -> xn1
    float* B_ = F + N_NODES * HD;        // 1.6M: xe -> aggE2 -> xe2
    float* E_ = B_ + N_HEDGES * HD;      // 1.6M: aggE1 -> xe1
    float* poolN = E_ + N_HEDGES * HD;   // 4096
    float* poolE = poolN + NG * HD;      // 4096
    float* cntBN = poolE + NG * HD;      // 64
    float* cntBE = cntBN + NG;           // 64
    int* gcntE = (int*)(cntBE + NG);     // 98
    int* gcntN = gcntE + EB_NB;          // 196
    int* off = gcntN + NB_NB;            // 125000
    int* deg = off + (N_HEDGES + N_NODES);          // 125000
    int* binE = deg + (N_HEDGES + N_NODES);         // 98*12000 = 1,176,000
    int* binN = binE + EB_NB * EB_CAP;              // 196*6200 = 1,215,200
    int* srtE = binN + NB_NB * NB_CAP;              // 1,176,000
    int* srtN = srtE + EB_NB * EB_CAP;              // 1,215,200

    const int Bt = 256;

    // ---- zero: pools (8192) + cntB (128) + gcnt (294) contiguous ----
    int zeroN = 2 * NG * HD + 2 * NG + EB_NB + NB_NB;
    zero_words<<<(zeroN + Bt - 1) / Bt, Bt, 0, stream>>>((int*)poolN, zeroN);

    // ---- binned CSR build (2 kernels) ----
    bin_pass<<<2 * TPS, Bt, 0, stream>>>(n2e_src, n2e_dst, e2n_src, e2n_dst,
                                         binE, binN, gcntE, gcntN);
    fine_fill<<<EB_NB + NB_NB, 512, 0, stream>>>(binE, binN, gcntE, gcntN,
                                                 off, deg, srtE, srtN);

    // ---- encoders (xn -> A, xe -> B_) ----
    encode_fused<<<((N_NODES + N_HEDGES) * HD + Bt - 1) / Bt, Bt, 0, stream>>>(
        node_x, edge_x, Wn, bn, We, be, A, B_);

    int gbE = (N_HEDGES + 63) / 64;  // 391
    int gbN = (N_NODES + 63) / 64;   // 1563
    int gridC = gbE + gbN;           // 1954
    int gridG = 2048;

    // ---- layer 1 ----
    gather_layer<<<gridG, Bt, 0, stream>>>(A, B_, off, deg, srtE, srtN, E_, F);
    combine_layer<<<gridC, Bt, 0, stream>>>(E_, B_, F, A,
                                            W1l_n2e, b1l_n2e, W1r_n2e,
                                            W1l_e2n, b1l_e2n, W1r_e2n,
                                            E_ /*xe1*/, F /*xn1*/, gbE);

    // ---- layer 2 ----
    gather_layer<<<gridG, Bt, 0, stream>>>(F, E_, off, deg, srtE, srtN, B_, A);
    combine_layer<<<gridC, Bt, 0, stream>>>(B_, E_, A, F,
                                            W2l_n2e, b2l_n2e, W2r_n2e,
                                            W2l_e2n, b2l_e2n, W2r_e2n,
                                            B_ /*xe2*/, A /*xn2*/, gbE);

    // ---- pooling + readout ----
    pool_sorted<<<NG * PB_N + NG * PB_E, Bt, 0, stream>>>(A, B_, node_batch, edge_batch, poolN, poolE);
    batch_counts_bs<<<1, 128, 0, stream>>>(node_batch, edge_batch, cntBN, cntBE);
    final_kernel<<<(NG * 32 + Bt - 1) / Bt, Bt, 0, stream>>>(poolN, poolE, cntBN, cntBE, Wout, bout, out);
}

// Round 7
// 310.514 us; speedup vs baseline: 6.5117x; 1.0282x over previous
//
#include <hip/hip_runtime.h>

#define N_NODES 100000
#define N_HEDGES 25000
#define N_EDGES 1000000
#define NG 64
#define HD 64

// binned CSR build params
#define EB_SH 8
#define EB_NB 98      // ceil(25000/256)
#define EB_CAP 12000
#define NB_SH 9
#define NB_NB 196     // ceil(100000/512)
#define NB_CAP 6200
#define TILE 4096
#define TPS 245       // tiles per side
#define ENC_F4 ((N_NODES + N_HEDGES) * 16)  // 2,000,000 f4 elements

typedef __attribute__((ext_vector_type(4))) float f4;

__global__ void zero_words(int* p, int n) {
    int i = blockIdx.x * blockDim.x + threadIdx.x;
    if (i < n) p[i] = 0;
}

// ---------------- pass 1: LDS-binned scatter + (fused) encoder ----------------
__global__ __launch_bounds__(256) void bin_encode(
    const int* __restrict__ n2e_src, const int* __restrict__ n2e_dst,
    const int* __restrict__ e2n_src, const int* __restrict__ e2n_dst,
    int* __restrict__ binE, int* __restrict__ binN,
    int* __restrict__ gcntE, int* __restrict__ gcntN,
    const float* __restrict__ node_x, const float* __restrict__ edge_x,
    const float* __restrict__ Wn, const float* __restrict__ bn,
    const float* __restrict__ We, const float* __restrict__ be,
    float* __restrict__ xn, float* __restrict__ xe) {
    __shared__ int pairsL[TILE];
    __shared__ int hist[256], scanv[256], start[256], curs[256], gbase[256];
    int t = threadIdx.x;
    if ((int)blockIdx.x >= 2 * TPS) {
        // ---- encoder path ----
        int i4 = ((int)blockIdx.x - 2 * TPS) * 256 + t;
        if (i4 < N_NODES * 16) {
            int row = i4 >> 4, fq = i4 & 15;
            f4 wn = *(const f4*)(Wn + fq * 4);
            f4 bnv = *(const f4*)(bn + fq * 4);
            float xv = node_x[row];
            f4 v;
#pragma unroll
            for (int c = 0; c < 4; c++) v[c] = fmaxf(xv * wn[c] + bnv[c], 0.f);
            *(f4*)(xn + (long)i4 * 4) = v;
        } else if (i4 < ENC_F4) {
            int j = i4 - N_NODES * 16;
            int row = j >> 4, fq = j & 15;
            f4 w0 = *(const f4*)(We + fq * 4);
            f4 w1 = *(const f4*)(We + HD + fq * 4);
            f4 bev = *(const f4*)(be + fq * 4);
            float x0 = edge_x[2 * row], x1 = edge_x[2 * row + 1];
            f4 v;
#pragma unroll
            for (int c = 0; c < 4; c++) v[c] = fmaxf(x0 * w0[c] + x1 * w1[c] + bev[c], 0.f);
            *(f4*)(xe + (long)j * 4) = v;
        }
        return;
    }
    // ---- binning path ----
    int side = (int)blockIdx.x >= TPS;
    int lb = blockIdx.x - (side ? TPS : 0);
    const int* dsts = side ? e2n_dst : n2e_dst;
    const int* srcs = side ? e2n_src : n2e_src;
    int NB = side ? NB_NB : EB_NB;
    int SH = side ? NB_SH : EB_SH;
    int CAP = side ? NB_CAP : EB_CAP;
    int* bins = side ? binN : binE;
    int* gcnt = side ? gcntN : gcntE;
    int base = lb * TILE;

    hist[t] = 0;
    __syncthreads();

    int pair[16], buck[16];
#pragma unroll
    for (int k = 0; k < 16; k++) {
        int e = base + k * 256 + t;
        if (e < N_EDGES) {
            int d = dsts[e];
            int s = srcs[e];
            buck[k] = d >> SH;
            pair[k] = ((d & ((1 << SH) - 1)) << 17) | s;
            atomicAdd(&hist[buck[k]], 1);
        } else buck[k] = -1;
    }
    __syncthreads();
    int v = hist[t];
    scanv[t] = v;
    __syncthreads();
    for (int o = 1; o < 256; o <<= 1) {
        int x = (t >= o) ? scanv[t - o] : 0;
        __syncthreads();
        scanv[t] += x;
        __syncthreads();
    }
    start[t] = scanv[t] - v;
    curs[t] = scanv[t] - v;
    if (t < NB && v > 0) gbase[t] = t * CAP + atomicAdd(&gcnt[t], v);
    __syncthreads();
    int total = scanv[255];
#pragma unroll
    for (int k = 0; k < 16; k++) {
        if (buck[k] >= 0) {
            int slot = atomicAdd(&curs[buck[k]], 1);
            pairsL[slot] = pair[k];
        }
    }
    __syncthreads();
    for (int i = t; i < total; i += 256) {
        int lo = 0, hi = NB - 1;
        while (lo < hi) { int mid = (lo + hi + 1) >> 1; if (start[mid] <= i) lo = mid; else hi = mid - 1; }
        bins[gbase[lo] + (i - start[lo])] = pairsL[i];
    }
}

// ---------------- pass 2: per-bucket fine CSR fill ----------------
__global__ __launch_bounds__(512) void fine_fill(
    const int* __restrict__ binE, const int* __restrict__ binN,
    const int* __restrict__ gcntE, const int* __restrict__ gcntN,
    int* __restrict__ off, int* __restrict__ deg,
    int* __restrict__ srtE, int* __restrict__ srtN) {
    __shared__ int hist[512], scanv[512];
    int t = threadIdx.x;
    int side = (int)blockIdx.x >= EB_NB;
    int b = blockIdx.x - (side ? EB_NB : 0);
    int NROWS = side ? 512 : 256;
    int CAP = side ? NB_CAP : EB_CAP;
    const int* bins = (side ? binN : binE) + (long)b * CAP;
    int* srt = (side ? srtN : srtE) + (long)b * CAP;
    int cnt_b = (side ? gcntN : gcntE)[b];
    int rowbase = side ? (N_HEDGES + b * 512) : b * 256;
    int nrows = (side ? N_NODES : N_HEDGES) - (side ? b * 512 : b * 256);
    if (nrows > NROWS) nrows = NROWS;

    hist[t] = 0;
    __syncthreads();
    for (int i = t; i < cnt_b; i += 512) atomicAdd(&hist[bins[i] >> 17], 1);
    __syncthreads();
    int v = hist[t];
    scanv[t] = v;
    __syncthreads();
    for (int o = 1; o < 512; o <<= 1) {
        int x = (t >= o) ? scanv[t - o] : 0;
        __syncthreads();
        scanv[t] += x;
        __syncthreads();
    }
    int excl = scanv[t] - v;
    if (t < nrows) { off[rowbase + t] = b * CAP + excl; deg[rowbase + t] = v; }
    scanv[t] = excl;
    __syncthreads();
    for (int i = t; i < cnt_b; i += 512) {
        int p = bins[i];
        int pos = atomicAdd(&scanv[p >> 17], 1);
        srt[pos] = p & 0x1FFFF;
    }
}

// ---------------- gather-mean: 4-deep load chains ----------------
__global__ __launch_bounds__(256) void gather_layer(
    const float* __restrict__ xnFeat, const float* __restrict__ xeFeat,
    const int* __restrict__ off, const int* __restrict__ deg,
    const int* __restrict__ srtE, const int* __restrict__ srtN,
    float* __restrict__ aggE, float* __restrict__ aggN) {
    int lane = threadIdx.x & 63;
    int w = blockIdx.x * 4 + (threadIdx.x >> 6);
    int NW = gridDim.x * 4;
    int esub = lane >> 4;
    int fq = lane & 15;
    const int RT = N_HEDGES + N_NODES;
    for (int r = w; r < RT; r += NW) {
        const float* xsrc; const int* srt; float* agg; int rr, idx;
        if (r < N_HEDGES) {
            rr = r; idx = rr;
            xsrc = xnFeat; srt = srtE; agg = aggE;
        } else {
            rr = r - N_HEDGES; idx = N_HEDGES + rr;
            xsrc = xeFeat; srt = srtN; agg = aggN;
        }
        int lo = off[idx];
        int dg = deg[idx];
        f4 a0 = {0.f,0.f,0.f,0.f}, a1 = a0, a2 = a0, a3 = a0;
        for (int j0 = 0; j0 < dg; j0 += 64) {
            int chunk = dg - j0;
            if (chunk > 64) chunk = 64;
            int idv = (j0 + lane < dg) ? srt[lo + j0 + lane] : 0;
            int jj = 0;
            for (; jj + 16 <= chunk; jj += 16) {
                int s0 = __shfl(idv, jj + esub);
                int s1 = __shfl(idv, jj + 4 + esub);
                int s2 = __shfl(idv, jj + 8 + esub);
                int s3 = __shfl(idv, jj + 12 + esub);
                a0 += *(const f4*)(xsrc + (long)s0 * HD + fq * 4);
                a1 += *(const f4*)(xsrc + (long)s1 * HD + fq * 4);
                a2 += *(const f4*)(xsrc + (long)s2 * HD + fq * 4);
                a3 += *(const f4*)(xsrc + (long)s3 * HD + fq * 4);
            }
            for (; jj < chunk; jj += 8) {
                int e0 = jj + esub, e1 = jj + 4 + esub;
                int s0 = __shfl(idv, e0 & 63);
                int s1 = __shfl(idv, e1 & 63);
                if (e0 < chunk) a0 += *(const f4*)(xsrc + (long)s0 * HD + fq * 4);
                if (e1 < chunk) a1 += *(const f4*)(xsrc + (long)s1 * HD + fq * 4);
            }
        }
        f4 acc = (a0 + a1) + (a2 + a3);
#pragma unroll
        for (int c = 0; c < 4; c++) {
            acc[c] += __shfl_xor(acc[c], 16);
            acc[c] += __shfl_xor(acc[c], 32);
        }
        if (lane < 16) {
            float invd = 1.f / (float)(dg > 1 ? dg : 1);
            *(f4*)(agg + (long)rr * HD + fq * 4) = acc * invd;
        }
    }
}

// ---------------- combine: out = relu(agg@Wl + bl + xdst@Wr), in-place ----------------
__device__ __forceinline__ void combine_body(
    const float* agg, const float* __restrict__ xdst,
    const float* __restrict__ Wl, const float* __restrict__ bl, const float* __restrict__ Wr,
    float* out, int rows, int row0) {
    __shared__ float sW0[32 * 64];
    __shared__ float sW1[32 * 64];
    __shared__ float sA[64][68];
    __shared__ float sX[64][68];

    int t = threadIdx.x;
    {
        int r = t >> 2, c0s = (t & 3) * 16;
        int gr = row0 + r;
        if (gr < rows) {
            const f4* ga = (const f4*)(agg + (long)gr * HD + c0s);
            const f4* gx = (const f4*)(xdst + (long)gr * HD + c0s);
            f4* la = (f4*)&sA[r][c0s];
            f4* lx = (f4*)&sX[r][c0s];
#pragma unroll
            for (int q = 0; q < 4; q++) { la[q] = ga[q]; lx[q] = gx[q]; }
        }
    }

    int tc = t & 15, tr = t >> 4;
    int c0 = tc * 4, m0 = tr * 4;
    f4 acc[4];
    f4 blv = *(const f4*)(bl + c0);
#pragma unroll
    for (int i = 0; i < 4; i++) acc[i] = blv;

    for (int half = 0; half < 2; half++) {
        __syncthreads();
        for (int i = t; i < 32 * 64; i += 256) {
            sW0[i] = Wl[half * 2048 + i];
            sW1[i] = Wr[half * 2048 + i];
        }
        __syncthreads();
#pragma unroll
        for (int kq = 0; kq < 8; kq++) {
            int k0 = kq * 4;
            int ka = half * 32 + k0;
            f4 wl[4], wr[4];
#pragma unroll
            for (int kk = 0; kk < 4; kk++) {
                wl[kk] = *(const f4*)&sW0[(k0 + kk) * 64 + c0];
                wr[kk] = *(const f4*)&sW1[(k0 + kk) * 64 + c0];
            }
#pragma unroll
            for (int i = 0; i < 4; i++) {
                f4 a = *(const f4*)&sA[m0 + i][ka];
                f4 x = *(const f4*)&sX[m0 + i][ka];
#pragma unroll
                for (int kk = 0; kk < 4; kk++)
                    acc[i] += a[kk] * wl[kk] + x[kk] * wr[kk];
            }
        }
    }

#pragma unroll
    for (int i = 0; i < 4; i++) {
        int gr = row0 + m0 + i;
        if (gr < rows) {
            f4 v = acc[i];
#pragma unroll
            for (int j = 0; j < 4; j++) v[j] = fmaxf(v[j], 0.f);
            *(f4*)(out + (long)gr * HD + c0) = v;
        }
    }
}

__global__ __launch_bounds__(256) void combine_layer(
    const float* aggE, const float* __restrict__ xeDst,
    const float* aggN, const float* __restrict__ xnDst,
    const float* __restrict__ WlE, const float* __restrict__ blE, const float* __restrict__ WrE,
    const float* __restrict__ WlN, const float* __restrict__ blN, const float* __restrict__ WrN,
    float* outE, float* outN, int gbE) {
    if ((int)blockIdx.x < gbE)
        combine_body(aggE, xeDst, WlE, blE, WrE, outE, N_HEDGES, blockIdx.x * 64);
    else
        combine_body(aggN, xnDst, WlN, blN, WrN, outN, N_NODES, (blockIdx.x - gbE) * 64);
}

// ---------------- fused pooling + readout: one block per graph ----------------
__device__ __forceinline__ int lower_bound_dev(const int* arr, int n, int key) {
    int lo = 0, hi = n;
    while (lo < hi) { int mid = (lo + hi) >> 1; if (arr[mid] < key) lo = mid + 1; else hi = mid; }
    return lo;
}

__global__ __launch_bounds__(256) void pool_final(
    const float* __restrict__ xn2, const float* __restrict__ xe2,
    const int* __restrict__ node_batch, const int* __restrict__ edge_batch,
    const float* __restrict__ Wout, const float* __restrict__ bout,
    float* __restrict__ out) {
    __shared__ float sPool[2][64];
    __shared__ f4 sPart[4][16];
    int g = blockIdx.x;
    int t = threadIdx.x;
    int lane = t & 63, w = t >> 6;
    int fq = lane & 15, sub = lane >> 4;

    for (int side = 0; side < 2; side++) {
        const float* x = side ? xe2 : xn2;
        const int* batch = side ? edge_batch : node_batch;
        int n = side ? N_HEDGES : N_NODES;
        int s = lower_bound_dev(batch, n, g);
        int e2 = lower_bound_dev(batch, n, g + 1);
        int len = e2 - s;
        f4 acc = {0.f, 0.f, 0.f, 0.f};
        for (int r = s + w * 4 + sub; r < e2; r += 16)
            acc += *(const f4*)(x + (long)r * HD + fq * 4);
#pragma unroll
        for (int c = 0; c < 4; c++) {
            acc[c] += __shfl_xor(acc[c], 16);
            acc[c] += __shfl_xor(acc[c], 32);
        }
        if (lane < 16) sPart[w][fq] = acc;
        __syncthreads();
        if (t < 16) {
            f4 v = sPart[0][t] + sPart[1][t] + sPart[2][t] + sPart[3][t];
            float inv = 1.f / (float)(len > 1 ? len : 1);
            v *= inv;
            *(f4*)&sPool[side][t * 4] = v;
        }
        __syncthreads();
    }
    if (t < 32) {
        float s = bout[t];
#pragma unroll 8
        for (int k = 0; k < HD; k++)
            s += sPool[0][k] * Wout[k * 32 + t] + sPool[1][k] * Wout[(HD + k) * 32 + t];
        out[g * 32 + t] = s;
    }
}

extern "C" void kernel_launch(void* const* d_in, const int* in_sizes, int n_in,
                              void* d_out, int out_size, void* d_ws, size_t ws_size,
                              hipStream_t stream) {
    const float* node_x = (const float*)d_in[0];
    const float* edge_x = (const float*)d_in[1];
    const int* n2e_src = (const int*)d_in[2];
    const int* n2e_dst = (const int*)d_in[3];
    const int* e2n_src = (const int*)d_in[4];
    const int* e2n_dst = (const int*)d_in[5];
    const int* node_batch = (const int*)d_in[6];
    const int* edge_batch = (const int*)d_in[7];
    const float* Wn = (const float*)d_in[8];
    const float* bn = (const float*)d_in[9];
    const float* We = (const float*)d_in[10];
    const float* be = (const float*)d_in[11];
    const float* W1l_n2e = (const float*)d_in[12];
    const float* b1l_n2e = (const float*)d_in[13];
    const float* W1r_n2e = (const float*)d_in[14];
    const float* W1l_e2n = (const float*)d_in[15];
    const float* b1l_e2n = (const float*)d_in[16];
    const float* W1r_e2n = (const float*)d_in[17];
    const float* W2l_n2e = (const float*)d_in[18];
    const float* b2l_n2e = (const float*)d_in[19];
    const float* W2r_n2e = (const float*)d_in[20];
    const float* W2l_e2n = (const float*)d_in[21];
    const float* b2l_e2n = (const float*)d_in[22];
    const float* W2r_e2n = (const float*)d_in[23];
    const float* Wout = (const float*)d_in[24];
    const float* bout = (const float*)d_in[25];
    float* out = (float*)d_out;

    // ---- workspace layout ----
    float* Wp = (float*)d_ws;
    float* A = Wp;                       // 6.4M: xn -> aggN2 -> xn2
    float* F = A + N_NODES * HD;         // 6.4M: aggN1 -> xn1
    float* B_ = F + N_NODES * HD;        // 1.6M: xe -> aggE2 -> xe2
    float* E_ = B_ + N_HEDGES * HD;      // 1.6M: aggE1 -> xe1
    int* gcntE = (int*)(E_ + N_HEDGES * HD);  // 98
    int* gcntN = gcntE + EB_NB;               // 196
    int* off = gcntN + NB_NB;                 // 125000
    int* deg = off + (N_HEDGES + N_NODES);    // 125000
    int* binE = deg + (N_HEDGES + N_NODES);   // 1,176,000
    int* binN = binE + EB_NB * EB_CAP;        // 1,215,200
    int* srtE = binN + NB_NB * NB_CAP;        // 1,176,000
    int* srtN = srtE + EB_NB * EB_CAP;        // 1,215,200

    const int Bt = 256;

    // 1) zero bucket cursors
    zero_words<<<2, Bt, 0, stream>>>(gcntE, EB_NB + NB_NB);

    // 2) binning + encoder (fused grid)
    int encBlocks = (ENC_F4 + Bt - 1) / Bt;  // 7813
    bin_encode<<<2 * TPS + encBlocks, Bt, 0, stream>>>(
        n2e_src, n2e_dst, e2n_src, e2n_dst, binE, binN, gcntE, gcntN,
        node_x, edge_x, Wn, bn, We, be, A, B_);

    // 3) fine CSR fill
    fine_fill<<<EB_NB + NB_NB, 512, 0, stream>>>(binE, binN, gcntE, gcntN,
                                                 off, deg, srtE, srtN);

    int gbE = (N_HEDGES + 63) / 64;  // 391
    int gbN = (N_NODES + 63) / 64;   // 1563
    int gridC = gbE + gbN;           // 1954

    // 4-5) layer 1
    gather_layer<<<2048, Bt, 0, stream>>>(A, B_, off, deg, srtE, srtN, E_, F);
    combine_layer<<<gridC, Bt, 0, stream>>>(E_, B_, F, A,
                                            W1l_n2e, b1l_n2e, W1r_n2e,
                                            W1l_e2n, b1l_e2n, W1r_e2n,
                                            E_ /*xe1*/, F /*xn1*/, gbE);

    // 6-7) layer 2
    gather_layer<<<2048, Bt, 0, stream>>>(F, E_, off, deg, srtE, srtN, B_, A);
    combine_layer<<<gridC, Bt, 0, stream>>>(B_, E_, A, F,
                                            W2l_n2e, b2l_n2e, W2r_n2e,
                                            W2l_e2n, b2l_e2n, W2r_e2n,
                                            B_ /*xe2*/, A /*xn2*/, gbE);

    // 8) fused pooling + readout
    pool_final<<<NG, Bt, 0, stream>>>(A, B_, node_batch, edge_batch, Wout, bout, out);
}

// Round 8
// 274.887 us; speedup vs baseline: 7.3556x; 1.1296x over previous
//
#include <hip/hip_runtime.h>

#define N_NODES 100000
#define N_HEDGES 25000
#define N_EDGES 1000000
#define NG 64
#define HD 64

// binned CSR build params
#define EB_SH 8
#define EB_NB 98      // ceil(25000/256)
#define EB_CAP 12000
#define NB_SH 9
#define NB_NB 196     // ceil(100000/512)
#define NB_CAP 6200
#define TILE 4096
#define TPS 245       // tiles per side
#define ENC_F4 ((N_NODES + N_HEDGES) * 16)  // 2,000,000 f4 elements

typedef __attribute__((ext_vector_type(4))) float f4;
typedef __attribute__((ext_vector_type(4))) unsigned short us4;

__device__ __forceinline__ unsigned short f2bf(float f) {
    unsigned int u = __float_as_uint(f);
    unsigned int r = (u + 0x7FFFu + ((u >> 16) & 1u)) >> 16;  // RNE
    return (unsigned short)r;
}
__device__ __forceinline__ f4 bf4_to_f4(us4 h) {
    f4 v;
    v[0] = __uint_as_float((unsigned int)h[0] << 16);
    v[1] = __uint_as_float((unsigned int)h[1] << 16);
    v[2] = __uint_as_float((unsigned int)h[2] << 16);
    v[3] = __uint_as_float((unsigned int)h[3] << 16);
    return v;
}
__device__ __forceinline__ us4 f4_to_bf4(f4 v) {
    us4 h;
    h[0] = f2bf(v[0]); h[1] = f2bf(v[1]); h[2] = f2bf(v[2]); h[3] = f2bf(v[3]);
    return h;
}

__global__ void zero_words(int* p, int n) {
    int i = blockIdx.x * blockDim.x + threadIdx.x;
    if (i < n) p[i] = 0;
}

// ---------------- pass 1: LDS-binned scatter + (fused) encoder ----------------
__global__ __launch_bounds__(256) void bin_encode(
    const int* __restrict__ n2e_src, const int* __restrict__ n2e_dst,
    const int* __restrict__ e2n_src, const int* __restrict__ e2n_dst,
    int* __restrict__ binE, int* __restrict__ binN,
    int* __restrict__ gcntE, int* __restrict__ gcntN,
    const float* __restrict__ node_x, const float* __restrict__ edge_x,
    const float* __restrict__ Wn, const float* __restrict__ bn,
    const float* __restrict__ We, const float* __restrict__ be,
    float* __restrict__ xn, float* __restrict__ xe,
    unsigned short* __restrict__ xnH, unsigned short* __restrict__ xeH) {
    __shared__ int pairsL[TILE];
    __shared__ int hist[256], scanv[256], start[256], curs[256], gbase[256];
    int t = threadIdx.x;
    if ((int)blockIdx.x >= 2 * TPS) {
        // ---- encoder path (fp32 + bf16 mirror) ----
        int i4 = ((int)blockIdx.x - 2 * TPS) * 256 + t;
        if (i4 < N_NODES * 16) {
            int row = i4 >> 4, fq = i4 & 15;
            f4 wn = *(const f4*)(Wn + fq * 4);
            f4 bnv = *(const f4*)(bn + fq * 4);
            float xv = node_x[row];
            f4 v;
#pragma unroll
            for (int c = 0; c < 4; c++) v[c] = fmaxf(xv * wn[c] + bnv[c], 0.f);
            *(f4*)(xn + (long)i4 * 4) = v;
            *(us4*)(xnH + (long)i4 * 4) = f4_to_bf4(v);
        } else if (i4 < ENC_F4) {
            int j = i4 - N_NODES * 16;
            int row = j >> 4, fq = j & 15;
            f4 w0 = *(const f4*)(We + fq * 4);
            f4 w1 = *(const f4*)(We + HD + fq * 4);
            f4 bev = *(const f4*)(be + fq * 4);
            float x0 = edge_x[2 * row], x1 = edge_x[2 * row + 1];
            f4 v;
#pragma unroll
            for (int c = 0; c < 4; c++) v[c] = fmaxf(x0 * w0[c] + x1 * w1[c] + bev[c], 0.f);
            *(f4*)(xe + (long)j * 4) = v;
            *(us4*)(xeH + (long)j * 4) = f4_to_bf4(v);
        }
        return;
    }
    // ---- binning path ----
    int side = (int)blockIdx.x >= TPS;
    int lb = blockIdx.x - (side ? TPS : 0);
    const int* dsts = side ? e2n_dst : n2e_dst;
    const int* srcs = side ? e2n_src : n2e_src;
    int NB = side ? NB_NB : EB_NB;
    int SH = side ? NB_SH : EB_SH;
    int CAP = side ? NB_CAP : EB_CAP;
    int* bins = side ? binN : binE;
    int* gcnt = side ? gcntN : gcntE;
    int base = lb * TILE;

    hist[t] = 0;
    __syncthreads();

    int pair[16], buck[16];
#pragma unroll
    for (int k = 0; k < 16; k++) {
        int e = base + k * 256 + t;
        if (e < N_EDGES) {
            int d = dsts[e];
            int s = srcs[e];
            buck[k] = d >> SH;
            pair[k] = ((d & ((1 << SH) - 1)) << 17) | s;
            atomicAdd(&hist[buck[k]], 1);
        } else buck[k] = -1;
    }
    __syncthreads();
    int v = hist[t];
    scanv[t] = v;
    __syncthreads();
    for (int o = 1; o < 256; o <<= 1) {
        int x = (t >= o) ? scanv[t - o] : 0;
        __syncthreads();
        scanv[t] += x;
        __syncthreads();
    }
    start[t] = scanv[t] - v;
    curs[t] = scanv[t] - v;
    if (t < NB && v > 0) gbase[t] = t * CAP + atomicAdd(&gcnt[t], v);
    __syncthreads();
    int total = scanv[255];
#pragma unroll
    for (int k = 0; k < 16; k++) {
        if (buck[k] >= 0) {
            int slot = atomicAdd(&curs[buck[k]], 1);
            pairsL[slot] = pair[k];
        }
    }
    __syncthreads();
    for (int i = t; i < total; i += 256) {
        int lo = 0, hi = NB - 1;
        while (lo < hi) { int mid = (lo + hi + 1) >> 1; if (start[mid] <= i) lo = mid; else hi = mid - 1; }
        bins[gbase[lo] + (i - start[lo])] = pairsL[i];
    }
}

// ---------------- pass 2: per-bucket fine CSR fill ----------------
__global__ __launch_bounds__(512) void fine_fill(
    const int* __restrict__ binE, const int* __restrict__ binN,
    const int* __restrict__ gcntE, const int* __restrict__ gcntN,
    int* __restrict__ off, int* __restrict__ deg,
    int* __restrict__ srtE, int* __restrict__ srtN) {
    __shared__ int hist[512], scanv[512];
    int t = threadIdx.x;
    int side = (int)blockIdx.x >= EB_NB;
    int b = blockIdx.x - (side ? EB_NB : 0);
    int NROWS = side ? 512 : 256;
    int CAP = side ? NB_CAP : EB_CAP;
    const int* bins = (side ? binN : binE) + (long)b * CAP;
    int* srt = (side ? srtN : srtE) + (long)b * CAP;
    int cnt_b = (side ? gcntN : gcntE)[b];
    int rowbase = side ? (N_HEDGES + b * 512) : b * 256;
    int nrows = (side ? N_NODES : N_HEDGES) - (side ? b * 512 : b * 256);
    if (nrows > NROWS) nrows = NROWS;

    hist[t] = 0;
    __syncthreads();
    for (int i = t; i < cnt_b; i += 512) atomicAdd(&hist[bins[i] >> 17], 1);
    __syncthreads();
    int v = hist[t];
    scanv[t] = v;
    __syncthreads();
    for (int o = 1; o < 512; o <<= 1) {
        int x = (t >= o) ? scanv[t - o] : 0;
        __syncthreads();
        scanv[t] += x;
        __syncthreads();
    }
    int excl = scanv[t] - v;
    if (t < nrows) { off[rowbase + t] = b * CAP + excl; deg[rowbase + t] = v; }
    scanv[t] = excl;
    __syncthreads();
    for (int i = t; i < cnt_b; i += 512) {
        int p = bins[i];
        int pos = atomicAdd(&scanv[p >> 17], 1);
        srt[pos] = p & 0x1FFFF;
    }
}

// ---------------- gather-mean from bf16 mirrors (2-chain, 8-edge groups) ----------------
__global__ __launch_bounds__(256) void gather_layer(
    const unsigned short* __restrict__ xnH, const unsigned short* __restrict__ xeH,
    const int* __restrict__ off, const int* __restrict__ deg,
    const int* __restrict__ srtE, const int* __restrict__ srtN,
    float* __restrict__ aggE, float* __restrict__ aggN) {
    int lane = threadIdx.x & 63;
    int w = blockIdx.x * 4 + (threadIdx.x >> 6);
    int NW = gridDim.x * 4;
    int esub = lane >> 4;
    int fq = lane & 15;
    const int RT = N_HEDGES + N_NODES;
    for (int r = w; r < RT; r += NW) {
        const unsigned short* xsrc; const int* srt; float* agg; int rr, idx;
        if (r < N_HEDGES) {
            rr = r; idx = rr;
            xsrc = xnH; srt = srtE; agg = aggE;
        } else {
            rr = r - N_HEDGES; idx = N_HEDGES + rr;
            xsrc = xeH; srt = srtN; agg = aggN;
        }
        int lo = off[idx];
        int dg = deg[idx];
        f4 a0 = {0.f, 0.f, 0.f, 0.f}, a1 = a0;
        for (int j0 = 0; j0 < dg; j0 += 64) {
            int chunk = dg - j0;
            if (chunk > 64) chunk = 64;
            int idv = (j0 + lane < dg) ? srt[lo + j0 + lane] : 0;
            int jj = 0;
            for (; jj + 8 <= chunk; jj += 8) {
                int s0 = __shfl(idv, jj + esub);
                int s1 = __shfl(idv, jj + 4 + esub);
                us4 h0 = ((const us4*)(xsrc + (long)s0 * HD))[fq];
                us4 h1 = ((const us4*)(xsrc + (long)s1 * HD))[fq];
                a0 += bf4_to_f4(h0);
                a1 += bf4_to_f4(h1);
            }
            for (; jj < chunk; jj += 4) {
                int e = jj + esub;
                int s = __shfl(idv, e & 63);
                us4 h = ((const us4*)(xsrc + (long)s * HD))[fq];
                if (e < chunk) a0 += bf4_to_f4(h);
            }
        }
        f4 acc = a0 + a1;
#pragma unroll
        for (int c = 0; c < 4; c++) {
            acc[c] += __shfl_xor(acc[c], 16);
            acc[c] += __shfl_xor(acc[c], 32);
        }
        if (lane < 16) {
            float invd = 1.f / (float)(dg > 1 ? dg : 1);
            *(f4*)(agg + (long)rr * HD + fq * 4) = acc * invd;
        }
    }
}

// ---------------- combine: out = relu(agg@Wl + bl + xdst@Wr), in-place; optional bf16 mirror ----------------
__device__ __forceinline__ void combine_body(
    const float* agg, const float* __restrict__ xdst,
    const float* __restrict__ Wl, const float* __restrict__ bl, const float* __restrict__ Wr,
    float* out, unsigned short* outH, int rows, int row0) {
    __shared__ float sW0[32 * 64];
    __shared__ float sW1[32 * 64];
    __shared__ float sA[64][68];
    __shared__ float sX[64][68];

    int t = threadIdx.x;
    {
        int r = t >> 2, c0s = (t & 3) * 16;
        int gr = row0 + r;
        if (gr < rows) {
            const f4* ga = (const f4*)(agg + (long)gr * HD + c0s);
            const f4* gx = (const f4*)(xdst + (long)gr * HD + c0s);
            f4* la = (f4*)&sA[r][c0s];
            f4* lx = (f4*)&sX[r][c0s];
#pragma unroll
            for (int q = 0; q < 4; q++) { la[q] = ga[q]; lx[q] = gx[q]; }
        }
    }

    int tc = t & 15, tr = t >> 4;
    int c0 = tc * 4, m0 = tr * 4;
    f4 acc[4];
    f4 blv = *(const f4*)(bl + c0);
#pragma unroll
    for (int i = 0; i < 4; i++) acc[i] = blv;

    for (int half = 0; half < 2; half++) {
        __syncthreads();
        for (int i = t; i < 32 * 64; i += 256) {
            sW0[i] = Wl[half * 2048 + i];
            sW1[i] = Wr[half * 2048 + i];
        }
        __syncthreads();
#pragma unroll
        for (int kq = 0; kq < 8; kq++) {
            int k0 = kq * 4;
            int ka = half * 32 + k0;
            f4 wl[4], wr[4];
#pragma unroll
            for (int kk = 0; kk < 4; kk++) {
                wl[kk] = *(const f4*)&sW0[(k0 + kk) * 64 + c0];
                wr[kk] = *(const f4*)&sW1[(k0 + kk) * 64 + c0];
            }
#pragma unroll
            for (int i = 0; i < 4; i++) {
                f4 a = *(const f4*)&sA[m0 + i][ka];
                f4 x = *(const f4*)&sX[m0 + i][ka];
#pragma unroll
                for (int kk = 0; kk < 4; kk++)
                    acc[i] += a[kk] * wl[kk] + x[kk] * wr[kk];
            }
        }
    }

#pragma unroll
    for (int i = 0; i < 4; i++) {
        int gr = row0 + m0 + i;
        if (gr < rows) {
            f4 v = acc[i];
#pragma unroll
            for (int j = 0; j < 4; j++) v[j] = fmaxf(v[j], 0.f);
            *(f4*)(out + (long)gr * HD + c0) = v;
            if (outH) *(us4*)(outH + (long)gr * HD + c0) = f4_to_bf4(v);
        }
    }
}

__global__ __launch_bounds__(256) void combine_layer(
    const float* aggE, const float* __restrict__ xeDst,
    const float* aggN, const float* __restrict__ xnDst,
    const float* __restrict__ WlE, const float* __restrict__ blE, const float* __restrict__ WrE,
    const float* __restrict__ WlN, const float* __restrict__ blN, const float* __restrict__ WrN,
    float* outE, float* outN,
    unsigned short* outEH, unsigned short* outNH, int gbE) {
    if ((int)blockIdx.x < gbE)
        combine_body(aggE, xeDst, WlE, blE, WrE, outE, outEH, N_HEDGES, blockIdx.x * 64);
    else
        combine_body(aggN, xnDst, WlN, blN, WrN, outN, outNH, N_NODES, (blockIdx.x - gbE) * 64);
}

// ---------------- fused pooling + readout: one block per graph ----------------
__device__ __forceinline__ int lower_bound_dev(const int* arr, int n, int key) {
    int lo = 0, hi = n;
    while (lo < hi) { int mid = (lo + hi) >> 1; if (arr[mid] < key) lo = mid + 1; else hi = mid; }
    return lo;
}

__global__ __launch_bounds__(256) void pool_final(
    const float* __restrict__ xn2, const float* __restrict__ xe2,
    const int* __restrict__ node_batch, const int* __restrict__ edge_batch,
    const float* __restrict__ Wout, const float* __restrict__ bout,
    float* __restrict__ out) {
    __shared__ float sPool[2][64];
    __shared__ f4 sPart[4][16];
    int g = blockIdx.x;
    int t = threadIdx.x;
    int lane = t & 63, w = t >> 6;
    int fq = lane & 15, sub = lane >> 4;

    for (int side = 0; side < 2; side++) {
        const float* x = side ? xe2 : xn2;
        const int* batch = side ? edge_batch : node_batch;
        int n = side ? N_HEDGES : N_NODES;
        int s = lower_bound_dev(batch, n, g);
        int e2 = lower_bound_dev(batch, n, g + 1);
        int len = e2 - s;
        f4 acc = {0.f, 0.f, 0.f, 0.f};
        for (int r = s + w * 4 + sub; r < e2; r += 16)
            acc += *(const f4*)(x + (long)r * HD + fq * 4);
#pragma unroll
        for (int c = 0; c < 4; c++) {
            acc[c] += __shfl_xor(acc[c], 16);
            acc[c] += __shfl_xor(acc[c], 32);
        }
        if (lane < 16) sPart[w][fq] = acc;
        __syncthreads();
        if (t < 16) {
            f4 v = sPart[0][t] + sPart[1][t] + sPart[2][t] + sPart[3][t];
            float inv = 1.f / (float)(len > 1 ? len : 1);
            v *= inv;
            *(f4*)&sPool[side][t * 4] = v;
        }
        __syncthreads();
    }
    if (t < 32) {
        float s = bout[t];
#pragma unroll 8
        for (int k = 0; k < HD; k++)
            s += sPool[0][k] * Wout[k * 32 + t] + sPool[1][k] * Wout[(HD + k) * 32 + t];
        out[g * 32 + t] = s;
    }
}

extern "C" void kernel_launch(void* const* d_in, const int* in_sizes, int n_in,
                              void* d_out, int out_size, void* d_ws, size_t ws_size,
                              hipStream_t stream) {
    const float* node_x = (const float*)d_in[0];
    const float* edge_x = (const float*)d_in[1];
    const int* n2e_src = (const int*)d_in[2];
    const int* n2e_dst = (const int*)d_in[3];
    const int* e2n_src = (const int*)d_in[4];
    const int* e2n_dst = (const int*)d_in[5];
    const int* node_batch = (const int*)d_in[6];
    const int* edge_batch = (const int*)d_in[7];
    const float* Wn = (const float*)d_in[8];
    const float* bn = (const float*)d_in[9];
    const float* We = (const float*)d_in[10];
    const float* be = (const float*)d_in[11];
    const float* W1l_n2e = (const float*)d_in[12];
    const float* b1l_n2e = (const float*)d_in[13];
    const float* W1r_n2e = (const float*)d_in[14];
    const float* W1l_e2n = (const float*)d_in[15];
    const float* b1l_e2n = (const float*)d_in[16];
    const float* W1r_e2n = (const float*)d_in[17];
    const float* W2l_n2e = (const float*)d_in[18];
    const float* b2l_n2e = (const float*)d_in[19];
    const float* W2r_n2e = (const float*)d_in[20];
    const float* W2l_e2n = (const float*)d_in[21];
    const float* b2l_e2n = (const float*)d_in[22];
    const float* W2r_e2n = (const float*)d_in[23];
    const float* Wout = (const float*)d_in[24];
    const float* bout = (const float*)d_in[25];
    float* out = (float*)d_out;

    // ---- workspace layout (~100 MB) ----
    float* Wp = (float*)d_ws;
    float* A = Wp;                       // 6.4M f32: xn -> aggN2 -> xn2
    float* F = A + N_NODES * HD;         // 6.4M: aggN1 -> xn1
    float* B_ = F + N_NODES * HD;        // 1.6M: xe -> aggE2 -> xe2
    float* E_ = B_ + N_HEDGES * HD;      // 1.6M: aggE1 -> xe1
    unsigned short* AH = (unsigned short*)(E_ + N_HEDGES * HD);  // 6.4M bf16: xnH -> xn1H
    unsigned short* BH = AH + N_NODES * HD;                      // 1.6M bf16: xeH -> xe1H
    int* gcntE = (int*)(BH + N_HEDGES * HD);  // 98
    int* gcntN = gcntE + EB_NB;               // 196
    int* off = gcntN + NB_NB;                 // 125000
    int* deg = off + (N_HEDGES + N_NODES);    // 125000
    int* binE = deg + (N_HEDGES + N_NODES);   // 1,176,000
    int* binN = binE + EB_NB * EB_CAP;        // 1,215,200
    int* srtE = binN + NB_NB * NB_CAP;        // 1,176,000
    int* srtN = srtE + EB_NB * EB_CAP;        // 1,215,200

    const int Bt = 256;

    // 1) zero bucket cursors
    zero_words<<<2, Bt, 0, stream>>>(gcntE, EB_NB + NB_NB);

    // 2) binning + encoder (fused grid)
    int encBlocks = (ENC_F4 + Bt - 1) / Bt;
    bin_encode<<<2 * TPS + encBlocks, Bt, 0, stream>>>(
        n2e_src, n2e_dst, e2n_src, e2n_dst, binE, binN, gcntE, gcntN,
        node_x, edge_x, Wn, bn, We, be, A, B_, AH, BH);

    // 3) fine CSR fill
    fine_fill<<<EB_NB + NB_NB, 512, 0, stream>>>(binE, binN, gcntE, gcntN,
                                                 off, deg, srtE, srtN);

    int gbE = (N_HEDGES + 63) / 64;  // 391
    int gbN = (N_NODES + 63) / 64;   // 1563
    int gridC = gbE + gbN;           // 1954

    // 4-5) layer 1: gather bf16 mirrors -> fp32 agg; combine writes fp32 + bf16 mirrors
    gather_layer<<<2048, Bt, 0, stream>>>(AH, BH, off, deg, srtE, srtN, E_, F);
    combine_layer<<<gridC, Bt, 0, stream>>>(E_, B_, F, A,
                                            W1l_n2e, b1l_n2e, W1r_n2e,
                                            W1l_e2n, b1l_e2n, W1r_e2n,
                                            E_ /*xe1*/, F /*xn1*/,
                                            BH /*xe1H*/, AH /*xn1H*/, gbE);

    // 6-7) layer 2: gather from xn1H/xe1H; no mirrors needed for outputs
    gather_layer<<<2048, Bt, 0, stream>>>(AH, BH, off, deg, srtE, srtN, B_, A);
    combine_layer<<<gridC, Bt, 0, stream>>>(B_, E_, A, F,
                                            W2l_n2e, b2l_n2e, W2r_n2e,
                                            W2l_e2n, b2l_e2n, W2r_e2n,
                                            B_ /*xe2*/, A /*xn2*/,
                                            (unsigned short*)nullptr, (unsigned short*)nullptr, gbE);

    // 8) fused pooling + readout
    pool_final<<<NG, Bt, 0, stream>>>(A, B_, node_batch, edge_batch, Wout, bout, out);
}

// Round 9
// 189.017 us; speedup vs baseline: 10.6972x; 1.4543x over previous
//
#include <hip/hip_runtime.h>

#define N_NODES 100000
#define N_HEDGES 25000
#define N_EDGES 1000000
#define NG 64
#define HD 64

// binned CSR build params
#define EB_SH 8
#define EB_NB 98
#define EB_CAP 12000
#define NB_SH 9
#define NB_NB 196
#define NB_CAP 6200
#define TILE 4096
#define TPS 245
#define ENC_F4 ((N_NODES + N_HEDGES) * 16)

typedef __attribute__((ext_vector_type(4))) float f4;
typedef __attribute__((ext_vector_type(4))) unsigned short us4;
typedef __attribute__((ext_vector_type(8))) unsigned short us8;
typedef __attribute__((ext_vector_type(8))) short s8b;   // MFMA bf16 A/B fragment

__device__ __forceinline__ unsigned short f2bf(float f) {
    unsigned int u = __float_as_uint(f);
    unsigned int r = (u + 0x7FFFu + ((u >> 16) & 1u)) >> 16;  // RNE
    return (unsigned short)r;
}
__device__ __forceinline__ float bf2f(unsigned short h) {
    return __uint_as_float((unsigned int)h << 16);
}
__device__ __forceinline__ us4 f4_to_bf4(f4 v) {
    us4 h;
    h[0] = f2bf(v[0]); h[1] = f2bf(v[1]); h[2] = f2bf(v[2]); h[3] = f2bf(v[3]);
    return h;
}

// ---------------- prep: W->Wt bf16 transpose (blocks 0-3) + zero (rest) ----------------
__global__ __launch_bounds__(256) void prep(
    const float* __restrict__ W1lE, const float* __restrict__ W1rE,
    const float* __restrict__ W1lN, const float* __restrict__ W1rN,
    const float* __restrict__ W2lE, const float* __restrict__ W2rE,
    const float* __restrict__ W2lN, const float* __restrict__ W2rN,
    unsigned short* __restrict__ WtH, int* __restrict__ zbase, int zn) {
    int b = blockIdx.x, t = threadIdx.x;
    if (b < 4) {
        const float *Wl, *Wr;
        switch (b) {
            case 0: Wl = W1lE; Wr = W1rE; break;
            case 1: Wl = W1lN; Wr = W1rN; break;
            case 2: Wl = W2lE; Wr = W2rE; break;
            default: Wl = W2lN; Wr = W2rN; break;
        }
        unsigned short* o = WtH + b * 8192;
        for (int idx = t; idx < 8192; idx += 256) {
            int c = idx >> 7, k = idx & 127;
            float v = (k < 64) ? Wl[k * 64 + c] : Wr[(k - 64) * 64 + c];
            o[c * 128 + k] = f2bf(v);  // Wt[col][k]: B^T layout
        }
    } else {
        int i = (b - 4) * 256 + t;
        if (i < zn) zbase[i] = 0;
    }
}

// ---------------- pass 1: LDS-binned scatter + fused encoder (bf16 out) ----------------
__global__ __launch_bounds__(256) void bin_encode(
    const int* __restrict__ n2e_src, const int* __restrict__ n2e_dst,
    const int* __restrict__ e2n_src, const int* __restrict__ e2n_dst,
    int* __restrict__ binE, int* __restrict__ binN,
    int* __restrict__ gcntE, int* __restrict__ gcntN,
    const float* __restrict__ node_x, const float* __restrict__ edge_x,
    const float* __restrict__ Wn, const float* __restrict__ bn,
    const float* __restrict__ We, const float* __restrict__ be,
    unsigned short* __restrict__ xnH, unsigned short* __restrict__ xeH) {
    __shared__ int pairsL[TILE];
    __shared__ int hist[256], scanv[256], start[256], curs[256], gbase[256];
    int t = threadIdx.x;
    if ((int)blockIdx.x >= 2 * TPS) {
        int i4 = ((int)blockIdx.x - 2 * TPS) * 256 + t;
        if (i4 < N_NODES * 16) {
            int row = i4 >> 4, fq = i4 & 15;
            f4 wn = *(const f4*)(Wn + fq * 4);
            f4 bnv = *(const f4*)(bn + fq * 4);
            float xv = node_x[row];
            f4 v;
#pragma unroll
            for (int c = 0; c < 4; c++) v[c] = fmaxf(xv * wn[c] + bnv[c], 0.f);
            *(us4*)(xnH + (long)i4 * 4) = f4_to_bf4(v);
        } else if (i4 < ENC_F4) {
            int j = i4 - N_NODES * 16;
            int row = j >> 4, fq = j & 15;
            f4 w0 = *(const f4*)(We + fq * 4);
            f4 w1 = *(const f4*)(We + HD + fq * 4);
            f4 bev = *(const f4*)(be + fq * 4);
            float x0 = edge_x[2 * row], x1 = edge_x[2 * row + 1];
            f4 v;
#pragma unroll
            for (int c = 0; c < 4; c++) v[c] = fmaxf(x0 * w0[c] + x1 * w1[c] + bev[c], 0.f);
            *(us4*)(xeH + (long)j * 4) = f4_to_bf4(v);
        }
        return;
    }
    int side = (int)blockIdx.x >= TPS;
    int lb = blockIdx.x - (side ? TPS : 0);
    const int* dsts = side ? e2n_dst : n2e_dst;
    const int* srcs = side ? e2n_src : n2e_src;
    int NB = side ? NB_NB : EB_NB;
    int SH = side ? NB_SH : EB_SH;
    int CAP = side ? NB_CAP : EB_CAP;
    int* bins = side ? binN : binE;
    int* gcnt = side ? gcntN : gcntE;
    int base = lb * TILE;

    hist[t] = 0;
    __syncthreads();

    int pair[16], buck[16];
#pragma unroll
    for (int k = 0; k < 16; k++) {
        int e = base + k * 256 + t;
        if (e < N_EDGES) {
            int d = dsts[e];
            int s = srcs[e];
            buck[k] = d >> SH;
            pair[k] = ((d & ((1 << SH) - 1)) << 17) | s;
            atomicAdd(&hist[buck[k]], 1);
        } else buck[k] = -1;
    }
    __syncthreads();
    int v = hist[t];
    scanv[t] = v;
    __syncthreads();
    for (int o = 1; o < 256; o <<= 1) {
        int x = (t >= o) ? scanv[t - o] : 0;
        __syncthreads();
        scanv[t] += x;
        __syncthreads();
    }
    start[t] = scanv[t] - v;
    curs[t] = scanv[t] - v;
    if (t < NB && v > 0) gbase[t] = t * CAP + atomicAdd(&gcnt[t], v);
    __syncthreads();
    int total = scanv[255];
#pragma unroll
    for (int k = 0; k < 16; k++) {
        if (buck[k] >= 0) {
            int slot = atomicAdd(&curs[buck[k]], 1);
            pairsL[slot] = pair[k];
        }
    }
    __syncthreads();
    for (int i = t; i < total; i += 256) {
        int lo = 0, hi = NB - 1;
        while (lo < hi) { int mid = (lo + hi + 1) >> 1; if (start[mid] <= i) lo = mid; else hi = mid - 1; }
        bins[gbase[lo] + (i - start[lo])] = pairsL[i];
    }
}

// ---------------- pass 2: per-bucket fine CSR fill ----------------
__global__ __launch_bounds__(512) void fine_fill(
    const int* __restrict__ binE, const int* __restrict__ binN,
    const int* __restrict__ gcntE, const int* __restrict__ gcntN,
    int* __restrict__ off, int* __restrict__ deg,
    int* __restrict__ srtE, int* __restrict__ srtN) {
    __shared__ int hist[512], scanv[512];
    int t = threadIdx.x;
    int side = (int)blockIdx.x >= EB_NB;
    int b = blockIdx.x - (side ? EB_NB : 0);
    int NROWS = side ? 512 : 256;
    int CAP = side ? NB_CAP : EB_CAP;
    const int* bins = (side ? binN : binE) + (long)b * CAP;
    int* srt = (side ? srtN : srtE) + (long)b * CAP;
    int cnt_b = (side ? gcntN : gcntE)[b];
    int rowbase = side ? (N_HEDGES + b * 512) : b * 256;
    int nrows = (side ? N_NODES : N_HEDGES) - (side ? b * 512 : b * 256);
    if (nrows > NROWS) nrows = NROWS;

    hist[t] = 0;
    __syncthreads();
    for (int i = t; i < cnt_b; i += 512) atomicAdd(&hist[bins[i] >> 17], 1);
    __syncthreads();
    int v = hist[t];
    scanv[t] = v;
    __syncthreads();
    for (int o = 1; o < 512; o <<= 1) {
        int x = (t >= o) ? scanv[t - o] : 0;
        __syncthreads();
        scanv[t] += x;
        __syncthreads();
    }
    int excl = scanv[t] - v;
    if (t < nrows) { off[rowbase + t] = b * CAP + excl; deg[rowbase + t] = v; }
    scanv[t] = excl;
    __syncthreads();
    for (int i = t; i < cnt_b; i += 512) {
        int p = bins[i];
        int pos = atomicAdd(&scanv[p >> 17], 1);
        srt[pos] = p & 0x1FFFF;
    }
}

// ---------------- gather-mean bf16 -> bf16 agg ----------------
__global__ __launch_bounds__(256) void gather_layer(
    const unsigned short* __restrict__ xnH, const unsigned short* __restrict__ xeH,
    const int* __restrict__ off, const int* __restrict__ deg,
    const int* __restrict__ srtE, const int* __restrict__ srtN,
    unsigned short* __restrict__ aggEH, unsigned short* __restrict__ aggNH) {
    int lane = threadIdx.x & 63;
    int w = blockIdx.x * 4 + (threadIdx.x >> 6);
    int NW = gridDim.x * 4;
    int esub = lane >> 4;
    int fq = lane & 15;
    const int RT = N_HEDGES + N_NODES;
    for (int r = w; r < RT; r += NW) {
        const unsigned short* xsrc; const int* srt; unsigned short* agg; int rr, idx;
        if (r < N_HEDGES) {
            rr = r; idx = rr;
            xsrc = xnH; srt = srtE; agg = aggEH;
        } else {
            rr = r - N_HEDGES; idx = N_HEDGES + rr;
            xsrc = xeH; srt = srtN; agg = aggNH;
        }
        int lo = off[idx];
        int dg = deg[idx];
        f4 a0 = {0.f, 0.f, 0.f, 0.f}, a1 = a0;
        for (int j0 = 0; j0 < dg; j0 += 64) {
            int chunk = dg - j0;
            if (chunk > 64) chunk = 64;
            int idv = (j0 + lane < dg) ? srt[lo + j0 + lane] : 0;
            int jj = 0;
            for (; jj + 8 <= chunk; jj += 8) {
                int s0 = __shfl(idv, jj + esub);
                int s1 = __shfl(idv, jj + 4 + esub);
                us4 h0 = ((const us4*)(xsrc + (long)s0 * HD))[fq];
                us4 h1 = ((const us4*)(xsrc + (long)s1 * HD))[fq];
#pragma unroll
                for (int c = 0; c < 4; c++) { a0[c] += bf2f(h0[c]); a1[c] += bf2f(h1[c]); }
            }
            for (; jj < chunk; jj += 4) {
                int e = jj + esub;
                int s = __shfl(idv, e & 63);
                us4 h = ((const us4*)(xsrc + (long)s * HD))[fq];
                if (e < chunk) {
#pragma unroll
                    for (int c = 0; c < 4; c++) a0[c] += bf2f(h[c]);
                }
            }
        }
        f4 acc = a0 + a1;
#pragma unroll
        for (int c = 0; c < 4; c++) {
            acc[c] += __shfl_xor(acc[c], 16);
            acc[c] += __shfl_xor(acc[c], 32);
        }
        if (lane < 16) {
            float invd = 1.f / (float)(dg > 1 ? dg : 1);
            *(us4*)(agg + (long)rr * HD + fq * 4) = f4_to_bf4(acc * invd);
        }
    }
}

// ---------------- combine via MFMA: out = relu([agg|xdst] @ [Wl;Wr] + bl), all bf16 ----------------
// Block = 64 rows; A-tile [64][128] bf16 (K=128 concat), Wt [64 cols][128 k] bf16 (B^T).
// mfma_f32_16x16x32_bf16: A lane l -> A[l&15][(l>>4)*8+j]; B lane l -> B[(l>>4)*8+j][l&15]
// (loaded from Wt[col][k], 8 consecutive k = 16B ds_read); C/D: col=l&15, row=(l>>4)*4+r (m89-verified).
__global__ __launch_bounds__(256) void combine_mfma(
    const unsigned short* __restrict__ aggEH, const unsigned short* __restrict__ xeH,
    const unsigned short* __restrict__ aggNH, const unsigned short* __restrict__ xnH,
    const unsigned short* __restrict__ WtE, const float* __restrict__ blE,
    const unsigned short* __restrict__ WtN, const float* __restrict__ blN,
    unsigned short* __restrict__ outEH, unsigned short* __restrict__ outNH, int gbE) {
    __shared__ unsigned short sA[64][136];  // pitch 136: rows 272B apart -> bank stride 4, 2-way max
    __shared__ unsigned short sW[64][136];
    int t = threadIdx.x;
    const unsigned short *aggH, *xdstH, *Wt;
    const float* bl;
    unsigned short* outH;
    int rows, row0;
    if ((int)blockIdx.x < gbE) {
        aggH = aggEH; xdstH = xeH; Wt = WtE; bl = blE; outH = outEH;
        rows = N_HEDGES; row0 = blockIdx.x * 64;
    } else {
        aggH = aggNH; xdstH = xnH; Wt = WtN; bl = blN; outH = outNH;
        rows = N_NODES; row0 = (blockIdx.x - gbE) * 64;
    }

    // stage Wt (64 rows x 16 us8-chunks) and A-tile ([agg|xdst])
#pragma unroll
    for (int q = 0; q < 4; q++) {
        int idx = q * 256 + t;
        int c = idx >> 4, ch = idx & 15;
        *(us8*)&sW[c][ch * 8] = *(const us8*)(Wt + c * 128 + ch * 8);
    }
#pragma unroll
    for (int q = 0; q < 4; q++) {
        int idx = q * 256 + t;
        int r = idx >> 4, ch = idx & 15;
        int gr = row0 + r;
        us8 v;
        if (gr < rows) {
            v = (ch < 8) ? *(const us8*)(aggH + (long)gr * HD + ch * 8)
                         : *(const us8*)(xdstH + (long)gr * HD + (ch - 8) * 8);
        } else {
            v = (us8){0, 0, 0, 0, 0, 0, 0, 0};
        }
        *(us8*)&sA[r][ch * 8] = v;
    }
    __syncthreads();

    int lane = t & 63, w = t >> 6;
    int m0 = w * 16;
    int l15 = lane & 15, quad = lane >> 4;
    f4 acc[4];
#pragma unroll
    for (int ct = 0; ct < 4; ct++) {
        float b = bl[ct * 16 + l15];
        acc[ct] = (f4){b, b, b, b};
    }
#pragma unroll
    for (int kb = 0; kb < 4; kb++) {
        s8b a = *(const s8b*)&sA[m0 + l15][kb * 32 + quad * 8];
#pragma unroll
        for (int ct = 0; ct < 4; ct++) {
            s8b bfr = *(const s8b*)&sW[ct * 16 + l15][kb * 32 + quad * 8];
            acc[ct] = __builtin_amdgcn_mfma_f32_16x16x32_bf16(a, bfr, acc[ct], 0, 0, 0);
        }
    }
#pragma unroll
    for (int ct = 0; ct < 4; ct++) {
#pragma unroll
        for (int r = 0; r < 4; r++) {
            int gr = row0 + m0 + quad * 4 + r;
            if (gr < rows) outH[(long)gr * HD + ct * 16 + l15] = f2bf(fmaxf(acc[ct][r], 0.f));
        }
    }
}

// ---------------- parallel pooling from bf16 feats ----------------
__device__ __forceinline__ int lower_bound_dev(const int* arr, int n, int key) {
    int lo = 0, hi = n;
    while (lo < hi) { int mid = (lo + hi) >> 1; if (arr[mid] < key) lo = mid + 1; else hi = mid; }
    return lo;
}

#define PB_N 8
#define PB_E 2
__global__ __launch_bounds__(256) void pool_bf(
    const unsigned short* __restrict__ xnH, const unsigned short* __restrict__ xeH,
    const int* __restrict__ node_batch, const int* __restrict__ edge_batch,
    float* __restrict__ poolN, float* __restrict__ poolE) {
    __shared__ float sp[4][64];
    int b = blockIdx.x;
    const unsigned short* x; const int* batch; float* pool; int n, g, part, P;
    if (b < NG * PB_N) { x = xnH; batch = node_batch; pool = poolN; n = N_NODES; g = b / PB_N; part = b % PB_N; P = PB_N; }
    else { b -= NG * PB_N; x = xeH; batch = edge_batch; pool = poolE; n = N_HEDGES; g = b / PB_E; part = b % PB_E; P = PB_E; }
    int s = lower_bound_dev(batch, n, g);
    int e = lower_bound_dev(batch, n, g + 1);
    int len = e - s;
    int start = s + (int)(((long)len * part) / P);
    int end = s + (int)(((long)len * (part + 1)) / P);
    int lane = threadIdx.x & 63, w = threadIdx.x >> 6;
    int fq = lane & 7, sub = lane >> 3;  // 8 chunks x 8 rows per wave
    f4 a0 = {0.f, 0.f, 0.f, 0.f}, a1 = a0;
    for (int r = start + w * 8 + sub; r < end; r += 32) {
        us8 h = *(const us8*)(x + (long)r * HD + fq * 8);
#pragma unroll
        for (int c = 0; c < 4; c++) { a0[c] += bf2f(h[c]); a1[c] += bf2f(h[c + 4]); }
    }
#pragma unroll
    for (int c = 0; c < 4; c++) {
        a0[c] += __shfl_xor(a0[c], 8);  a1[c] += __shfl_xor(a1[c], 8);
        a0[c] += __shfl_xor(a0[c], 16); a1[c] += __shfl_xor(a1[c], 16);
        a0[c] += __shfl_xor(a0[c], 32); a1[c] += __shfl_xor(a1[c], 32);
    }
    if (lane < 8) {
        *(f4*)&sp[w][fq * 8] = a0;
        *(f4*)&sp[w][fq * 8 + 4] = a1;
    }
    __syncthreads();
    if (threadIdx.x < 64) {
        int tt = threadIdx.x;
        float v = sp[0][tt] + sp[1][tt] + sp[2][tt] + sp[3][tt];
        if (v != 0.f) atomicAdd(&pool[g * HD + tt], v);
    }
}

// ---------------- final readout (one block per graph) ----------------
__global__ __launch_bounds__(64) void final_readout(
    const float* __restrict__ poolN, const float* __restrict__ poolE,
    const int* __restrict__ node_batch, const int* __restrict__ edge_batch,
    const float* __restrict__ Wout, const float* __restrict__ bout,
    float* __restrict__ out) {
    __shared__ float inv[2];
    int g = blockIdx.x, t = threadIdx.x;
    if (t < 2) {
        const int* arr = t ? edge_batch : node_batch;
        int n = t ? N_HEDGES : N_NODES;
        int lo = lower_bound_dev(arr, n, g);
        int hi = lower_bound_dev(arr, n, g + 1);
        int c = hi - lo;
        inv[t] = 1.f / (float)(c > 1 ? c : 1);
    }
    __syncthreads();
    if (t < 32) {
        float iN = inv[0], iE = inv[1];
        float s = bout[t];
#pragma unroll 8
        for (int k = 0; k < HD; k++)
            s += poolN[g * HD + k] * iN * Wout[k * 32 + t]
               + poolE[g * HD + k] * iE * Wout[(HD + k) * 32 + t];
        out[g * 32 + t] = s;
    }
}

extern "C" void kernel_launch(void* const* d_in, const int* in_sizes, int n_in,
                              void* d_out, int out_size, void* d_ws, size_t ws_size,
                              hipStream_t stream) {
    const float* node_x = (const float*)d_in[0];
    const float* edge_x = (const float*)d_in[1];
    const int* n2e_src = (const int*)d_in[2];
    const int* n2e_dst = (const int*)d_in[3];
    const int* e2n_src = (const int*)d_in[4];
    const int* e2n_dst = (const int*)d_in[5];
    const int* node_batch = (const int*)d_in[6];
    const int* edge_batch = (const int*)d_in[7];
    const float* Wn = (const float*)d_in[8];
    const float* bn = (const float*)d_in[9];
    const float* We = (const float*)d_in[10];
    const float* be = (const float*)d_in[11];
    const float* W1l_n2e = (const float*)d_in[12];
    const float* b1l_n2e = (const float*)d_in[13];
    const float* W1r_n2e = (const float*)d_in[14];
    const float* W1l_e2n = (const float*)d_in[15];
    const float* b1l_e2n = (const float*)d_in[16];
    const float* W1r_e2n = (const float*)d_in[17];
    const float* W2l_n2e = (const float*)d_in[18];
    const float* b2l_n2e = (const float*)d_in[19];
    const float* W2r_n2e = (const float*)d_in[20];
    const float* W2l_e2n = (const float*)d_in[21];
    const float* b2l_e2n = (const float*)d_in[22];
    const float* W2r_e2n = (const float*)d_in[23];
    const float* Wout = (const float*)d_in[24];
    const float* bout = (const float*)d_in[25];
    float* out = (float*)d_out;

    // ---- workspace layout (bf16 features; ~70 MB) ----
    unsigned short* AH0 = (unsigned short*)d_ws;        // 6.4M us: xn bf16 -> xn2
    unsigned short* BH0 = AH0 + N_NODES * HD;           // 1.6M: xe -> xe2
    unsigned short* AH1 = BH0 + N_HEDGES * HD;          // 6.4M: xn1
    unsigned short* BH1 = AH1 + N_NODES * HD;           // 1.6M: xe1
    unsigned short* aggNH = BH1 + N_HEDGES * HD;        // 6.4M
    unsigned short* aggEH = aggNH + N_NODES * HD;       // 1.6M
    unsigned short* WtH = aggEH + N_HEDGES * HD;        // 32768 (4 x [64][128])
    float* poolN = (float*)(WtH + 4 * 8192);            // 4096
    float* poolE = poolN + NG * HD;                     // 4096
    int* gcntE = (int*)(poolE + NG * HD);               // 98
    int* gcntN = gcntE + EB_NB;                         // 196
    int* off = gcntN + NB_NB;                           // 125000
    int* deg = off + (N_HEDGES + N_NODES);              // 125000
    int* binE = deg + (N_HEDGES + N_NODES);             // 1,176,000
    int* binN = binE + EB_NB * EB_CAP;                  // 1,215,200
    int* srtE = binN + NB_NB * NB_CAP;                  // 1,176,000
    int* srtN = srtE + EB_NB * EB_CAP;                  // 1,215,200

    const int Bt = 256;

    // 1) prep: Wt conversion + zero pools/cursors (contiguous: poolN..gcntN)
    int zn = 2 * NG * HD + EB_NB + NB_NB;  // 8486 words
    prep<<<4 + (zn + Bt - 1) / Bt, Bt, 0, stream>>>(
        W1l_n2e, W1r_n2e, W1l_e2n, W1r_e2n,
        W2l_n2e, W2r_n2e, W2l_e2n, W2r_e2n,
        WtH, (int*)poolN, zn);

    // 2) binning + encoder
    int encBlocks = (ENC_F4 + Bt - 1) / Bt;
    bin_encode<<<2 * TPS + encBlocks, Bt, 0, stream>>>(
        n2e_src, n2e_dst, e2n_src, e2n_dst, binE, binN, gcntE, gcntN,
        node_x, edge_x, Wn, bn, We, be, AH0, BH0);

    // 3) fine CSR fill
    fine_fill<<<EB_NB + NB_NB, 512, 0, stream>>>(binE, binN, gcntE, gcntN,
                                                 off, deg, srtE, srtN);

    int gbE = (N_HEDGES + 63) / 64;  // 391
    int gbN = (N_NODES + 63) / 64;   // 1563
    int gridC = gbE + gbN;

    // 4-5) layer 1
    gather_layer<<<2048, Bt, 0, stream>>>(AH0, BH0, off, deg, srtE, srtN, aggEH, aggNH);
    combine_mfma<<<gridC, Bt, 0, stream>>>(aggEH, BH0, aggNH, AH0,
                                           WtH, b1l_n2e, WtH + 8192, b1l_e2n,
                                           BH1, AH1, gbE);

    // 6-7) layer 2
    gather_layer<<<2048, Bt, 0, stream>>>(AH1, BH1, off, deg, srtE, srtN, aggEH, aggNH);
    combine_mfma<<<gridC, Bt, 0, stream>>>(aggEH, BH1, aggNH, AH1,
                                           WtH + 16384, b2l_n2e, WtH + 24576, b2l_e2n,
                                           BH0, AH0, gbE);

    // 8) pooling
    pool_bf<<<NG * PB_N + NG * PB_E, Bt, 0, stream>>>(AH0, BH0, node_batch, edge_batch, poolN, poolE);

    // 9) readout
    final_readout<<<NG, 64, 0, stream>>>(poolN, poolE, node_batch, edge_batch, Wout, bout, out);
}